// Round 11
// baseline (94.812 us; speedup 1.0000x reference)
//
#include <hip/hip_runtime.h>

#define MEPS 1e-6f
#define FINF 3.402823466e38f

typedef short bf16x8 __attribute__((ext_vector_type(8)));   // 8 bf16 (4 VGPRs)
typedef float f32x16 __attribute__((ext_vector_type(16)));  // MFMA 32x32 C/D

// bf16 round-to-nearest-even
__device__ __forceinline__ unsigned short bfr(float f) {
  unsigned u = __float_as_uint(f);
  return (unsigned short)((u + 0x7FFFu + ((u >> 16) & 1u)) >> 16);
}
__device__ __forceinline__ float bff(unsigned short h) {
  return __uint_as_float(((unsigned)h) << 16);
}
// Row-record (MFMA A-operand, b-points), 16 bf16 = 32B, k-schedule:
// [hx,hx,lx, hy,hy,ly, hz,hz,lz, hs,ls, 0...] pairing col [-2ahx,-2alx,-2ahx, ...,1,1]
__device__ __forceinline__ void writeRow(uint4* __restrict__ dst, int i,
                                         float x, float y, float z) {
  unsigned short hx = bfr(x); float fhx = bff(hx); unsigned short lx = bfr(x - fhx);
  unsigned short hy = bfr(y); float fhy = bff(hy); unsigned short ly = bfr(y - fhy);
  unsigned short hz = bfr(z); float fhz = bff(hz); unsigned short lz = bfr(z - fhz);
  float s = fmaf(x, x, fmaf(y, y, z * z));
  unsigned short hs = bfr(s); unsigned short ls = bfr(s - bff(hs));
  uint4 r0, r1;
  r0.x = (unsigned)hx | ((unsigned)hx << 16);
  r0.y = (unsigned)lx | ((unsigned)hy << 16);
  r0.z = (unsigned)hy | ((unsigned)ly << 16);
  r0.w = (unsigned)hz | ((unsigned)hz << 16);
  r1.x = (unsigned)lz | ((unsigned)hs << 16);
  r1.y = (unsigned)ls;
  r1.z = 0u; r1.w = 0u;
  dst[2*i] = r0; dst[2*i+1] = r1;
}

__device__ __forceinline__ float waveReduceAdd(float v) {
#pragma unroll
  for (int off = 32; off > 0; off >>= 1) v += __shfl_down(v, off, 64);
  return v;
}
__device__ __forceinline__ void blockRed1(float* red, float v, float* out) {
  int wave = threadIdx.x >> 6, lane = threadIdx.x & 63;
  v = waveReduceAdd(v);
  if (lane == 0) red[wave] = v;
  __syncthreads();
  if (threadIdx.x == 0) out[0] = red[0] + red[1] + red[2] + red[3];
}
__device__ __forceinline__ void blockRed2(float* red, float v0, float v1,
                                          float* o0, float* o1) {
  int wave = threadIdx.x >> 6, lane = threadIdx.x & 63;
  v0 = waveReduceAdd(v0); v1 = waveReduceAdd(v1);
  if (lane == 0) { red[wave] = v0; red[4 + wave] = v1; }
  __syncthreads();
  if (threadIdx.x == 0) {
    o0[0] = red[0] + red[1] + red[2] + red[3];
    o1[0] = red[4] + red[5] + red[6] + red[7];
  }
}
__device__ __forceinline__ void blockRed3(float* red, float v0, float v1, float v2,
                                          float* o0, float* o1, float* o2) {
  int wave = threadIdx.x >> 6, lane = threadIdx.x & 63;
  v0 = waveReduceAdd(v0); v1 = waveReduceAdd(v1); v2 = waveReduceAdd(v2);
  if (lane == 0) { red[wave] = v0; red[4 + wave] = v1; red[8 + wave] = v2; }
  __syncthreads();
  if (threadIdx.x == 0) {
    o0[0] = red[0] + red[1] + red[2] + red[3];
    o1[0] = red[4] + red[5] + red[6] + red[7];
    o2[0] = red[8] + red[9] + red[10] + red[11];
  }
}

// ---- K1: fused streaming pass + bf16 record emission. Branch uniform per block.
__global__ __launch_bounds__(256)
void k_geom(const float* __restrict__ verts, const float* __restrict__ deform,
            const float* __restrict__ vnorm, const float* __restrict__ bary,
            const int* __restrict__ faces, const int* __restrict__ edges,
            const int* __restrict__ sfi, const float* __restrict__ strg,
            float* __restrict__ nv, float* __restrict__ s_src,
            float* __restrict__ e012, float* __restrict__ fn_unit,
            float* __restrict__ fn_raw, float* __restrict__ elen,
            uint4* __restrict__ rrS, uint4* __restrict__ rrT, uint4* __restrict__ rrNf,
            float* __restrict__ pg0, float* __restrict__ pg1, float* __restrict__ pg2,
            int V, int F, int E, int Ns) {
  __shared__ float red[12];
  const int bid = blockIdx.x;
  const int idx = bid * 256 + threadIdx.x;
  const int VB = V >> 8, FB = F >> 8, EB = E >> 8, SB = Ns >> 8;
  if (bid < VB) {
    int i = idx;
    float dx = deform[3*i], dy = deform[3*i+1], dz = deform[3*i+2];
    float nx = verts[3*i] + dx, ny = verts[3*i+1] + dy, nz = verts[3*i+2] + dz;
    nv[3*i] = nx; nv[3*i+1] = ny; nv[3*i+2] = nz;
    writeRow(rrNf, i, -nx, ny, nz);   // flipped cloud (B-side of sym pass)
    float dot = dx*vnorm[3*i] + dy*vnorm[3*i+1] + dz*vnorm[3*i+2];
    blockRed1(red, fabsf(fminf(dot, -0.1f)), &pg0[bid]);
  } else if (bid < VB + FB) {
    int f = idx - V;
    int i0 = faces[3*f], i1 = faces[3*f+1], i2 = faces[3*f+2];
    float d0x = deform[3*i0], d0y = deform[3*i0+1], d0z = deform[3*i0+2];
    float d1x = deform[3*i1], d1y = deform[3*i1+1], d1z = deform[3*i1+2];
    float d2x = deform[3*i2], d2y = deform[3*i2+1], d2z = deform[3*i2+2];
    float v0x = verts[3*i0]+d0x, v0y = verts[3*i0+1]+d0y, v0z = verts[3*i0+2]+d0z;
    float v1x = verts[3*i1]+d1x, v1y = verts[3*i1+1]+d1y, v1z = verts[3*i1+2]+d1z;
    float v2x = verts[3*i2]+d2x, v2y = verts[3*i2+1]+d2y, v2z = verts[3*i2+2]+d2z;
    float e0 = sqrtf((v0x-v1x)*(v0x-v1x)+(v0y-v1y)*(v0y-v1y)+(v0z-v1z)*(v0z-v1z));
    float e1 = sqrtf((v1x-v2x)*(v1x-v2x)+(v1y-v2y)*(v1y-v2y)+(v1z-v2z)*(v1z-v2z));
    float e2 = sqrtf((v2x-v0x)*(v2x-v0x)+(v2y-v0y)*(v2y-v0y)+(v2z-v0z)*(v2z-v0z));
    e012[f] = e0; e012[F+f] = e1; e012[2*F+f] = e2;
    float ax = v1x-v0x, ay = v1y-v0y, az = v1z-v0z;
    float bx = v2x-v0x, by = v2y-v0y, bz = v2z-v0z;
    float fnx = ay*bz - az*by, fny = az*bx - ax*bz, fnz = ax*by - ay*bx;
    fn_raw[3*f] = fnx; fn_raw[3*f+1] = fny; fn_raw[3*f+2] = fnz;
    float inv = 1.0f / (sqrtf(fnx*fnx+fny*fny+fnz*fnz) + MEPS);
    fn_unit[3*f] = fnx*inv; fn_unit[3*f+1] = fny*inv; fn_unit[3*f+2] = fnz*inv;
    float s0 = sqrtf(d0x*d0x + d0y*d0y + d0z*d0z);
    float s1 = sqrtf(d1x*d1x + d1y*d1y + d1z*d1z);
    float s2 = sqrtf(d2x*d2x + d2y*d2y + d2z*d2z);
    blockRed3(red, e0 + e1 + e2,
              fabsf(e0-e1) + fabsf(e1-e2) + fabsf(e2-e0),
              fabsf(s0-s1) + fabsf(s1-s2) + fabsf(s2-s0),
              &pg0[bid], &pg1[bid], &pg2[bid]);
  } else if (bid < VB + FB + EB) {
    int e = idx - V - F;
    int a = edges[2*e], b = edges[2*e+1];
    float pax = verts[3*a]+deform[3*a], pay = verts[3*a+1]+deform[3*a+1], paz = verts[3*a+2]+deform[3*a+2];
    float pbx = verts[3*b]+deform[3*b], pby = verts[3*b+1]+deform[3*b+1], pbz = verts[3*b+2]+deform[3*b+2];
    elen[e] = sqrtf((pax-pbx)*(pax-pbx)+(pay-pby)*(pay-pby)+(paz-pbz)*(paz-pbz));
  } else if (bid < VB + FB + EB + SB) {
    int s = idx - V - F - E;
    int f = sfi[s];
    int i0 = faces[3*f], i1 = faces[3*f+1], i2 = faces[3*f+2];
    float w0 = bary[3*s], w1 = bary[3*s+1], w2 = bary[3*s+2];
    float sx = w0*(verts[3*i0]  +deform[3*i0])   + w1*(verts[3*i1]  +deform[3*i1])   + w2*(verts[3*i2]  +deform[3*i2]);
    float sy = w0*(verts[3*i0+1]+deform[3*i0+1]) + w1*(verts[3*i1+1]+deform[3*i1+1]) + w2*(verts[3*i2+1]+deform[3*i2+1]);
    float sz = w0*(verts[3*i0+2]+deform[3*i0+2]) + w1*(verts[3*i1+2]+deform[3*i1+2]) + w2*(verts[3*i2+2]+deform[3*i2+2]);
    s_src[3*s] = sx; s_src[3*s+1] = sy; s_src[3*s+2] = sz;
    writeRow(rrS, s, sx, sy, sz);
  } else {
    int t = idx - V - F - E - Ns;
    writeRow(rrT, t, strg[3*t], strg[3*t+1], strg[3*t+2]);
  }
}

// ---- K2: sliced range-gather (4 slices) + fused reduceG tail block (bid 512).
__global__ __launch_bounds__(256)
void k_scatterR(const int* __restrict__ faces, const int* __restrict__ edges,
                const float* __restrict__ fn_raw, const float* __restrict__ nv,
                float* __restrict__ psum,
                const float* __restrict__ pg0, const float* __restrict__ pg1,
                const float* __restrict__ pg2, float* __restrict__ acc,
                int V, int F, int E) {
  const int tid = threadIdx.x;
  const int bid = blockIdx.x;
  if (bid == 512) {  // reduceG
    __shared__ float red[16];
    int wave = tid >> 6, lane = tid & 63;
    const int VB = V >> 8, FB = F >> 8;
    float pen = 0, es = 0, l1 = 0, sm = 0;
    for (int i = tid; i < VB; i += 256) pen += pg0[i];
    for (int i = VB + tid; i < VB + FB; i += 256) { es += pg0[i]; l1 += pg1[i]; sm += pg2[i]; }
    pen = waveReduceAdd(pen); es = waveReduceAdd(es);
    l1 = waveReduceAdd(l1);   sm = waveReduceAdd(sm);
    if (lane == 0) { red[wave] = pen; red[4+wave] = es; red[8+wave] = l1; red[12+wave] = sm; }
    __syncthreads();
    if (tid == 0) {
      acc[11] = red[0]+red[1]+red[2]+red[3];
      acc[0]  = red[4]+red[5]+red[6]+red[7];
      acc[1]  = red[8]+red[9]+red[10]+red[11];
      acc[5]  = red[12]+red[13]+red[14]+red[15];
    }
    return;
  }
  __shared__ float lds[4][256];
#pragma unroll
  for (int c = 0; c < 4; ++c) lds[c][tid] = 0.f;
  __syncthreads();
  if (bid < 256) {
    int r = bid & 63, s = bid >> 6;
    int base = r << 8;
    int fs = F >> 2;
    for (int f = s*fs + tid; f < s*fs + fs; f += 256) {
      int i0 = faces[3*f], i1 = faces[3*f+1], i2 = faces[3*f+2];
      unsigned r0 = (unsigned)(i0-base), r1 = (unsigned)(i1-base), r2 = (unsigned)(i2-base);
      if ((r0 < 256u) | (r1 < 256u) | (r2 < 256u)) {
        float fx = fn_raw[3*f], fy = fn_raw[3*f+1], fz = fn_raw[3*f+2];
        if (r0 < 256u) { atomicAdd(&lds[0][r0],fx); atomicAdd(&lds[1][r0],fy); atomicAdd(&lds[2][r0],fz); }
        if (r1 < 256u) { atomicAdd(&lds[0][r1],fx); atomicAdd(&lds[1][r1],fy); atomicAdd(&lds[2][r1],fz); }
        if (r2 < 256u) { atomicAdd(&lds[0][r2],fx); atomicAdd(&lds[1][r2],fy); atomicAdd(&lds[2][r2],fz); }
      }
    }
    __syncthreads();
#pragma unroll
    for (int c = 0; c < 3; ++c) psum[(size_t)(s*7 + 4 + c)*V + base + tid] = lds[c][tid];
  } else {
    int b2 = bid - 256;
    int r = b2 & 63, s = b2 >> 6;
    int base = r << 8;
    int es = E >> 2;
    for (int e = s*es + tid; e < s*es + es; e += 256) {
      int a = edges[2*e], b = edges[2*e+1];
      unsigned ra = (unsigned)(a-base), rb = (unsigned)(b-base);
      if (ra < 256u) {
        atomicAdd(&lds[0][ra], nv[3*b]); atomicAdd(&lds[1][ra], nv[3*b+1]);
        atomicAdd(&lds[2][ra], nv[3*b+2]); atomicAdd(&lds[3][ra], 1.0f);
      }
      if (rb < 256u) {
        atomicAdd(&lds[0][rb], nv[3*a]); atomicAdd(&lds[1][rb], nv[3*a+1]);
        atomicAdd(&lds[2][rb], nv[3*a+2]); atomicAdd(&lds[3][rb], 1.0f);
      }
    }
    __syncthreads();
#pragma unroll
    for (int c = 0; c < 4; ++c) psum[(size_t)(s*7 + c)*V + base + tid] = lds[c][tid];
  }
}

__device__ __forceinline__ void vfinBody(const float* __restrict__ psum,
                                         const float* __restrict__ nv,
                                         const float* __restrict__ vnorm,
                                         float* red, int v, int V,
                                         float* o0, float* o1) {
  float nbx=0, nby=0, nbz=0, dg=0, vx=0, vy=0, vz=0;
#pragma unroll
  for (int s = 0; s < 4; ++s) {
    nbx += psum[(size_t)(s*7+0)*V + v];
    nby += psum[(size_t)(s*7+1)*V + v];
    nbz += psum[(size_t)(s*7+2)*V + v];
    dg  += psum[(size_t)(s*7+3)*V + v];
    vx  += psum[(size_t)(s*7+4)*V + v];
    vy  += psum[(size_t)(s*7+5)*V + v];
    vz  += psum[(size_t)(s*7+6)*V + v];
  }
  float inv = 1.0f / fmaxf(dg, 1.0f);
  float lx = nbx*inv - nv[3*v];
  float ly = nby*inv - nv[3*v+1];
  float lz = nbz*inv - nv[3*v+2];
  float lap = sqrtf(lx*lx + ly*ly + lz*lz);
  float vinv = 1.0f / (sqrtf(vx*vx + vy*vy + vz*vz) + MEPS);
  float dx = vx*vinv - vnorm[3*v];
  float dy = vy*vinv - vnorm[3*v+1];
  float dz = vz*vinv - vnorm[3*v+2];
  blockRed2(red, lap, dx*dx + dy*dy + dz*dz, o0, o1);
}

__global__ __launch_bounds__(256)
void k_vfinSolo(const float* __restrict__ psum, const float* __restrict__ nv,
                const float* __restrict__ vnorm,
                float* __restrict__ pl0, float* __restrict__ pl1, int V) {
  __shared__ float red[8];
  vfinBody(psum, nv, vnorm, red, blockIdx.x*256 + threadIdx.x, V,
           &pl0[blockIdx.x], &pl1[blockIdx.x]);
}

// left-chained so clang fuses to v_min3_f32
__device__ __forceinline__ float m3(float a, float b, float c) {
  return fminf(fminf(a, b), c);
}
__device__ __forceinline__ float rmin16(float m, f32x16 d) {
  float u0 = m3(d[0],  d[1],  d[2]);
  float u1 = m3(d[3],  d[4],  d[5]);
  float u2 = m3(d[6],  d[7],  d[8]);
  float u3 = m3(d[9],  d[10], d[11]);
  float u4 = m3(d[12], d[13], d[14]);
  float v0 = m3(u0, u1, u2);
  float v1 = m3(u3, u4, d[15]);
  return m3(m, v0, v1);
}

// ---- K3: MFMA chamfer, all three passes in one launch.
// Block = 4 waves x 128 a-cols = 512 a-points; chunk = STAGES x 512 b-records.
// Software-pipelined staging (T14): next stage's 4 global loads are issued
// right after the LDS-ready barrier, so L2 latency hides under the 16-bt
// MFMA+min compute; vmcnt-wait lands at the next stage's ds_write.
template<int STAGES>
__global__ __launch_bounds__(256, 4)
void k_chamM(const uint4* __restrict__ rrS, const uint4* __restrict__ rrT,
             const uint4* __restrict__ rrNf,
             float* __restrict__ pch1, float* __restrict__ pch2, float* __restrict__ pch3,
             int Ns, int Nt, int V) {
  __shared__ uint4 sH[2][512];           // [half][record] = 16 KB
  const int tid = threadIdx.x;
  const int wv = tid >> 6, ln = tid & 63;
  const int col = ln & 31, half = ln >> 5;
  const int shC = (STAGES == 4) ? 11 : 12;   // chunk = STAGES*512
  const int aT1 = Ns >> 9, aT2 = Nt >> 9, aT3 = V >> 9;
  const int nb1 = Nt >> shC, nb2 = Ns >> shC;
  const int B1 = aT1 * nb1, B2 = B1 + aT2 * nb2;
  const int bid = blockIdx.x;
  const uint4 *cr, *rr; float* pch; int at, bc, Na; float sx;
  if (bid < B1)      { cr = rrS;  rr = rrT;  pch = pch1; Na = Ns; at = bid % aT1; bc = bid / aT1; sx = -2.f; }
  else if (bid < B2) { int l = bid - B1; cr = rrT;  rr = rrS;  pch = pch2; Na = Nt; at = l % aT2; bc = l / aT2; sx = -2.f; }
  else               { int l = bid - B2; cr = rrNf; rr = rrNf; pch = pch3; Na = V;  at = l % aT3; bc = l / aT3; sx = 2.f; }
  // sx=+2 for sym pass: rrNf stores -x; col side needs -2*(+x) = +2*(-x).
  const int aBase = (at << 9) + (wv << 7);

  // Build 4 col-frag (B-operand) sets from the col cloud's records.
  bf16x8 bfrag[4];
#pragma unroll
  for (int s = 0; s < 4; ++s) {
    const uint4* crp = cr + ((size_t)(aBase + (s << 5) + col) << 1);
    uint4 q0 = crp[0], q1 = crp[1];
    unsigned short e0 = (unsigned short)(q0.x & 0xFFFFu);
    unsigned short e2 = (unsigned short)(q0.y & 0xFFFFu);
    unsigned short e3 = (unsigned short)(q0.y >> 16);
    unsigned short e5 = (unsigned short)(q0.z >> 16);
    unsigned short e6 = (unsigned short)(q0.w & 0xFFFFu);
    unsigned short e8 = (unsigned short)(q1.x & 0xFFFFu);
    unsigned short a0 = bfr(sx   * bff(e0));   // +-2*hx
    unsigned short a1 = bfr(sx   * bff(e2));   // +-2*lx
    unsigned short a3 = bfr(-2.f * bff(e3));   // -2*hy
    unsigned short a4 = bfr(-2.f * bff(e5));   // -2*ly
    unsigned short a6 = bfr(-2.f * bff(e6));   // -2*hz
    unsigned short a7 = bfr(-2.f * bff(e8));   // -2*lz
    uint4 bb;
    if (half == 0) {           // k0..7
      bb.x = (unsigned)a0 | ((unsigned)a1 << 16);
      bb.y = (unsigned)a0 | ((unsigned)a3 << 16);
      bb.z = (unsigned)a4 | ((unsigned)a3 << 16);
      bb.w = (unsigned)a6 | ((unsigned)a7 << 16);
    } else {                   // k8..15: [-2hz, 1, 1, 0...]
      bb.x = (unsigned)a6 | (0x3F80u << 16);
      bb.y = 0x3F80u;
      bb.z = 0u; bb.w = 0u;
    }
    bfrag[s] = __builtin_bit_cast(bf16x8, bb);
  }

  float m0 = FINF, m1 = FINF, m2 = FINF, m3v = FINF;
  f32x16 zz = {0.f,0.f,0.f,0.f,0.f,0.f,0.f,0.f,0.f,0.f,0.f,0.f,0.f,0.f,0.f,0.f};
  const int bBase = bc << shC;

  // prologue: load stage 0 into registers
  uint4 stg[4];
  {
    const uint4* src = rr + ((size_t)bBase << 1);
#pragma unroll
    for (int i = 0; i < 4; ++i) stg[i] = src[tid + (i << 8)];
  }
#pragma unroll 1
  for (int st = 0; st < STAGES; ++st) {
    __syncthreads();           // previous compute done; LDS free
#pragma unroll
    for (int i = 0; i < 4; ++i) {
      int idx = tid + (i << 8);
      sH[idx & 1][idx >> 1] = stg[i];   // (vmcnt wait folds here)
    }
    __syncthreads();           // LDS ready
    if (st + 1 < STAGES) {     // issue next stage's loads NOW; hide under compute
      const uint4* src = rr + ((size_t)(bBase + ((st + 1) << 9)) << 1);
#pragma unroll
      for (int i = 0; i < 4; ++i) stg[i] = src[tid + (i << 8)];
    }
    const bf16x8* lp = (const bf16x8*)sH[half];
    bf16x8 af = lp[col];
#pragma unroll
    for (int bt = 0; bt < 16; ++bt) {
      bf16x8 cur = af;
      if (bt < 15) af = lp[((bt + 1) << 5) + col];   // prefetch next record-frag
      {
        f32x16 d = __builtin_amdgcn_mfma_f32_32x32x16_bf16(cur, bfrag[0], zz, 0, 0, 0);
        m0 = rmin16(m0, d);
      }
      {
        f32x16 d = __builtin_amdgcn_mfma_f32_32x32x16_bf16(cur, bfrag[1], zz, 0, 0, 0);
        m1 = rmin16(m1, d);
      }
      {
        f32x16 d = __builtin_amdgcn_mfma_f32_32x32x16_bf16(cur, bfrag[2], zz, 0, 0, 0);
        m2 = rmin16(m2, d);
      }
      {
        f32x16 d = __builtin_amdgcn_mfma_f32_32x32x16_bf16(cur, bfrag[3], zz, 0, 0, 0);
        m3v = rmin16(m3v, d);
      }
    }
  }
  float mm0 = fminf(m0,  __shfl_xor(m0, 32));
  float mm1 = fminf(m1,  __shfl_xor(m1, 32));
  float mm2 = fminf(m2,  __shfl_xor(m2, 32));
  float mm3 = fminf(m3v, __shfl_xor(m3v, 32));
  if (ln < 32) {
    size_t base = (size_t)bc * Na + aBase + col;
    pch[base]      = mm0;
    pch[base + 32] = mm1;
    pch[base + 64] = mm2;
    pch[base + 96] = mm3;
  }
}

// ---- K4: fused finalize: chamfer per-point (a^2 + min over chunks) partials,
// avg-dependent terms, (optionally) vfin.
__global__ __launch_bounds__(256)
void k_fin(const float* __restrict__ pch1, const float* __restrict__ pch2,
           const float* __restrict__ pch3,
           const float* __restrict__ s_src, const float* __restrict__ s_trg,
           const float* __restrict__ nv, float* __restrict__ pc,
           const int* __restrict__ fpairs, const float* __restrict__ fn_unit,
           const float* __restrict__ e012, const float* __restrict__ elen,
           const float* __restrict__ acc, float* __restrict__ pf0,
           const float* __restrict__ psum, const float* __restrict__ vnorm,
           float* __restrict__ pl0, float* __restrict__ pl1,
           int Ns, int Nt, int V, int c1, int c2, int c3,
           int P, int F, int E) {
  __shared__ float red[8];
  const int bid = blockIdx.x;
  const int tid = threadIdx.x;
  const int chamB = (Ns + Nt + V) >> 8;
  const int finB = (P + F + E) >> 8;
  if (bid < chamB) {
    int idx = bid * 256 + tid;
    const float* A; const float* pch; int li, nc, Na;
    if (idx < Ns)           { A = s_src; pch = pch1; li = idx;           nc = c1; Na = Ns; }
    else if (idx < Ns + Nt) { A = s_trg; pch = pch2; li = idx - Ns;      nc = c2; Na = Nt; }
    else                    { A = nv;    pch = pch3; li = idx - Ns - Nt; nc = c3; Na = V; }
    float mn = FINF;
#pragma unroll 4
    for (int c = 0; c < nc; ++c) mn = fminf(mn, pch[(size_t)c * Na + li]);
    float x = A[3*li], y = A[3*li+1], z = A[3*li+2];
    blockRed1(red, x*x + y*y + z*z + mn, &pc[bid]);
  } else if (bid < chamB + finB) {
    int idx = (bid - chamB) * 256 + tid;
    const int PB = P >> 8, FB = F >> 8;
    float avg = acc[0] / (3.0f * (float)F);
    float val;
    if (bid - chamB < PB) {
      int f0 = fpairs[2*idx], f1 = fpairs[2*idx+1];
      val = 1.0f - (fn_unit[3*f0]*fn_unit[3*f1] + fn_unit[3*f0+1]*fn_unit[3*f1+1]
                  + fn_unit[3*f0+2]*fn_unit[3*f1+2]);
    } else if (bid - chamB < PB + FB) {
      int f = idx - P;
      val = fabsf(e012[f]-avg) + fabsf(e012[F+f]-avg) + fabsf(e012[2*F+f]-avg);
    } else {
      float d = elen[idx - P - F] - avg;
      val = d * d;
    }
    blockRed1(red, val, &pf0[bid - chamB]);
  } else {
    int vb = bid - chamB - finB;
    vfinBody(psum, nv, vnorm, red, vb*256 + tid, V, &pl0[vb], &pl1[vb]);
  }
}

// ---- K5: final combine (1 block)
__global__ void k_combine(const float* __restrict__ pf0, const float* __restrict__ pl0,
                          const float* __restrict__ pl1, const float* __restrict__ pc,
                          const float* __restrict__ acc, float* __restrict__ out,
                          int V, int F, int E, int P, int Ns, int Nt) {
  __shared__ float red[8][4];
  int tid = threadIdx.x, wave = tid >> 6, lane = tid & 63;
  const int PB = P >> 8, FB = F >> 8, EB = E >> 8, VB = V >> 8, NsB = Ns >> 8, NtB = Nt >> 8;
  float s0=0,s1=0,s2=0,s3=0,s4=0,s5=0,s6=0,s7=0;
  for (int i = tid; i < PB; i += 256) s0 += pf0[i];
  for (int i = tid; i < FB; i += 256) s1 += pf0[PB + i];
  for (int i = tid; i < EB; i += 256) s2 += pf0[PB + FB + i];
  for (int i = tid; i < VB; i += 256) { s3 += pl0[i]; s4 += pl1[i]; }
  for (int i = tid; i < NsB; i += 256) s5 += pc[i];
  for (int i = tid; i < NtB; i += 256) s6 += pc[NsB + i];
  for (int i = tid; i < VB; i += 256) s7 += pc[NsB + NtB + i];
  s0=waveReduceAdd(s0); s1=waveReduceAdd(s1); s2=waveReduceAdd(s2); s3=waveReduceAdd(s3);
  s4=waveReduceAdd(s4); s5=waveReduceAdd(s5); s6=waveReduceAdd(s6); s7=waveReduceAdd(s7);
  if (lane == 0) { red[0][wave]=s0; red[1][wave]=s1; red[2][wave]=s2; red[3][wave]=s3;
                   red[4][wave]=s4; red[5][wave]=s5; red[6][wave]=s6; red[7][wave]=s7; }
  __syncthreads();
  if (tid == 0) {
    float t[8];
#pragma unroll
    for (int c = 0; c < 8; ++c) t[c] = red[c][0]+red[c][1]+red[c][2]+red[c][3];
    float loss = t[5]/(float)Ns + t[6]/(float)Nt;         // chamfer
    loss += 0.1f * ((acc[1] + t[1]) / (float)F);          // face
    loss += 0.1f * (t[2] / (float)E);                     // edge
    loss += 0.1f * (t[0] / (float)P);                     // normal
    loss += 0.1f * (acc[5] / (float)F);                   // smooth
    loss += 0.1f * (t[3] / (float)V);                     // laplacian
    loss += 0.5f * (t[4] / (3.0f * (float)V));            // consistency
    loss += 0.1f * (2.0f * t[7] / (float)V);              // symmetry (flip isometry)
    loss += 5.0f * (acc[11] / (float)V);                  // penetration
    out[0] = loss;
  }
}

extern "C" void kernel_launch(void* const* d_in, const int* in_sizes, int n_in,
                              void* d_out, int out_size, void* d_ws, size_t ws_size,
                              hipStream_t stream) {
  const float* verts   = (const float*)d_in[0];
  const float* deform  = (const float*)d_in[1];
  const float* bary    = (const float*)d_in[2];
  const float* s_trg   = (const float*)d_in[3];
  const float* vnorm   = (const float*)d_in[4];
  const int*   faces   = (const int*)d_in[5];
  const int*   edges   = (const int*)d_in[6];
  const int*   fpairs  = (const int*)d_in[7];
  const int*   sfi     = (const int*)d_in[8];
  float* out = (float*)d_out;

  const int V  = in_sizes[0] / 3;
  const int Ns = in_sizes[2] / 3;
  const int Nt = in_sizes[3] / 3;
  const int F  = in_sizes[5] / 3;
  const int E  = in_sizes[6] / 2;
  const int P  = in_sizes[7] / 2;

  float* ws   = (float*)d_ws;
  float* acc  = ws;                                   // 16
  float* pg0  = ws + 16;                              // 256
  float* pg1  = pg0 + 256;                            // 256
  float* pg2  = pg1 + 256;                            // 256
  float* pf0  = pg2 + 256;                            // 512
  float* pl0  = pf0 + 512;                            // 64
  float* pl1  = pl0 + 64;                             // 64
  float* pc   = pl1 + 64;                             // 256
  float* nv    = pc + 256;                            // 3V
  float* s_src = nv + 3*V;                            // 3Ns
  float* fn_u  = s_src + 3*Ns;                        // 3F
  float* fn_r  = fn_u + 3*F;                          // 3F
  float* e012  = fn_r + 3*F;                          // 3F
  float* elen  = e012 + 3*F;                          // E
  float* psum  = elen + E;                            // 28V
  float* recF  = psum + 28*V;                         // 8*(Ns+Nt+V)
  uint4* rrS  = (uint4*)recF;
  uint4* rrT  = (uint4*)(recF + 8*Ns);
  uint4* rrNf = (uint4*)(recF + 8*Ns + 8*Nt);

  size_t fixedEnd = (size_t)(recF - ws) + 8*(size_t)(Ns + Nt + V);
  size_t wsFloats = ws_size / sizeof(float);
  // config A: 2048-b chunks (STAGES=4) disjoint; B: 4096 (STAGES=8) disjoint; C: 4096 aliased
  int nb1_2 = Nt >> 11, nb2_2 = Ns >> 11, nb3_2 = V >> 11;
  int nb1_4 = Nt >> 12, nb2_4 = Ns >> 12, nb3_4 = V >> 12;
  size_t pch2F = (size_t)nb1_2*Ns + (size_t)nb2_2*Nt + (size_t)nb3_2*V;
  size_t pch4F = (size_t)nb1_4*Ns + (size_t)nb2_4*Nt + (size_t)nb3_4*V;
  int stages; bool disjoint;
  int nb1, nb2, nb3;
  if (fixedEnd + pch2F <= wsFloats)      { stages = 4; disjoint = true;  nb1=nb1_2; nb2=nb2_2; nb3=nb3_2; }
  else if (fixedEnd + pch4F <= wsFloats) { stages = 8; disjoint = true;  nb1=nb1_4; nb2=nb2_4; nb3=nb3_4; }
  else                                   { stages = 8; disjoint = false; nb1=nb1_4; nb2=nb2_4; nb3=nb3_4; }
  float* pchBase = disjoint ? (recF + 8*(Ns + Nt + V)) : psum;
  float* pch1 = pchBase;
  float* pch2 = pch1 + (size_t)nb1 * Ns;
  float* pch3 = pch2 + (size_t)nb2 * Nt;

  int nGeom = (V + F + E + Ns + Nt) / 256;
  k_geom<<<nGeom, 256, 0, stream>>>(verts, deform, vnorm, bary, faces, edges, sfi,
                                    s_trg, nv, s_src, e012, fn_u, fn_r, elen,
                                    rrS, rrT, rrNf, pg0, pg1, pg2, V, F, E, Ns);
  k_scatterR<<<513, 256, 0, stream>>>(faces, edges, fn_r, nv, psum,
                                      pg0, pg1, pg2, acc, V, F, E);
  if (!disjoint)   // pch will overwrite psum -> finish laplacian/consistency first
    k_vfinSolo<<<V/256, 256, 0, stream>>>(psum, nv, vnorm, pl0, pl1, V);

  int nCham = (Ns >> 9) * nb1 + (Nt >> 9) * nb2 + (V >> 9) * nb3;
  if (stages == 4)
    k_chamM<4><<<nCham, 256, 0, stream>>>(rrS, rrT, rrNf, pch1, pch2, pch3, Ns, Nt, V);
  else
    k_chamM<8><<<nCham, 256, 0, stream>>>(rrS, rrT, rrNf, pch1, pch2, pch3, Ns, Nt, V);

  int chamB = (Ns + Nt + V) >> 8, finB = (P + F + E) >> 8;
  int vfinB = disjoint ? (V >> 8) : 0;
  k_fin<<<chamB + finB + vfinB, 256, 0, stream>>>(pch1, pch2, pch3, s_src, s_trg, nv, pc,
                                                  fpairs, fn_u, e012, elen, acc, pf0,
                                                  psum, vnorm, pl0, pl1,
                                                  Ns, Nt, V, nb1, nb2, nb3, P, F, E);
  k_combine<<<1, 256, 0, stream>>>(pf0, pl0, pl1, pc, acc, out, V, F, E, P, Ns, Nt);
}

// Round 12
// 85.404 us; speedup vs baseline: 1.1102x; 1.1102x over previous
//
#include <hip/hip_runtime.h>

#define MEPS 1e-6f
#define FINF 3.402823466e38f

typedef short bf16x8 __attribute__((ext_vector_type(8)));   // 8 bf16 (4 VGPRs)
typedef float f32x16 __attribute__((ext_vector_type(16)));  // MFMA 32x32 C/D

// async 16B global->LDS DMA (no VGPR round-trip)
__device__ __forceinline__ void load_lds16(const uint4* g, uint4* l) {
  __builtin_amdgcn_global_load_lds(
      (const __attribute__((address_space(1))) unsigned int*)g,
      (__attribute__((address_space(3))) unsigned int*)l, 16, 0, 0);
}

// bf16 round-to-nearest-even
__device__ __forceinline__ unsigned short bfr(float f) {
  unsigned u = __float_as_uint(f);
  return (unsigned short)((u + 0x7FFFu + ((u >> 16) & 1u)) >> 16);
}
__device__ __forceinline__ float bff(unsigned short h) {
  return __uint_as_float(((unsigned)h) << 16);
}
// Row-record (MFMA A-operand, b-points), 16 bf16 = 32B, k-schedule:
// [hx,hx,lx, hy,hy,ly, hz,hz,lz, hs,ls, 0...] pairing col [-2ahx,-2alx,-2ahx, ...,1,1]
__device__ __forceinline__ void writeRow(uint4* __restrict__ dst, int i,
                                         float x, float y, float z) {
  unsigned short hx = bfr(x); float fhx = bff(hx); unsigned short lx = bfr(x - fhx);
  unsigned short hy = bfr(y); float fhy = bff(hy); unsigned short ly = bfr(y - fhy);
  unsigned short hz = bfr(z); float fhz = bff(hz); unsigned short lz = bfr(z - fhz);
  float s = fmaf(x, x, fmaf(y, y, z * z));
  unsigned short hs = bfr(s); unsigned short ls = bfr(s - bff(hs));
  uint4 r0, r1;
  r0.x = (unsigned)hx | ((unsigned)hx << 16);
  r0.y = (unsigned)lx | ((unsigned)hy << 16);
  r0.z = (unsigned)hy | ((unsigned)ly << 16);
  r0.w = (unsigned)hz | ((unsigned)hz << 16);
  r1.x = (unsigned)lz | ((unsigned)hs << 16);
  r1.y = (unsigned)ls;
  r1.z = 0u; r1.w = 0u;
  dst[2*i] = r0; dst[2*i+1] = r1;
}

__device__ __forceinline__ float waveReduceAdd(float v) {
#pragma unroll
  for (int off = 32; off > 0; off >>= 1) v += __shfl_down(v, off, 64);
  return v;
}
__device__ __forceinline__ void blockRed1(float* red, float v, float* out) {
  int wave = threadIdx.x >> 6, lane = threadIdx.x & 63;
  v = waveReduceAdd(v);
  if (lane == 0) red[wave] = v;
  __syncthreads();
  if (threadIdx.x == 0) out[0] = red[0] + red[1] + red[2] + red[3];
}
__device__ __forceinline__ void blockRed2(float* red, float v0, float v1,
                                          float* o0, float* o1) {
  int wave = threadIdx.x >> 6, lane = threadIdx.x & 63;
  v0 = waveReduceAdd(v0); v1 = waveReduceAdd(v1);
  if (lane == 0) { red[wave] = v0; red[4 + wave] = v1; }
  __syncthreads();
  if (threadIdx.x == 0) {
    o0[0] = red[0] + red[1] + red[2] + red[3];
    o1[0] = red[4] + red[5] + red[6] + red[7];
  }
}
__device__ __forceinline__ void blockRed3(float* red, float v0, float v1, float v2,
                                          float* o0, float* o1, float* o2) {
  int wave = threadIdx.x >> 6, lane = threadIdx.x & 63;
  v0 = waveReduceAdd(v0); v1 = waveReduceAdd(v1); v2 = waveReduceAdd(v2);
  if (lane == 0) { red[wave] = v0; red[4 + wave] = v1; red[8 + wave] = v2; }
  __syncthreads();
  if (threadIdx.x == 0) {
    o0[0] = red[0] + red[1] + red[2] + red[3];
    o1[0] = red[4] + red[5] + red[6] + red[7];
    o2[0] = red[8] + red[9] + red[10] + red[11];
  }
}

// ---- K1: fused streaming pass + bf16 record emission. Branch uniform per block.
__global__ __launch_bounds__(256)
void k_geom(const float* __restrict__ verts, const float* __restrict__ deform,
            const float* __restrict__ vnorm, const float* __restrict__ bary,
            const int* __restrict__ faces, const int* __restrict__ edges,
            const int* __restrict__ sfi, const float* __restrict__ strg,
            float* __restrict__ nv, float* __restrict__ s_src,
            float* __restrict__ e012, float* __restrict__ fn_unit,
            float* __restrict__ fn_raw, float* __restrict__ elen,
            uint4* __restrict__ rrS, uint4* __restrict__ rrT, uint4* __restrict__ rrNf,
            float* __restrict__ pg0, float* __restrict__ pg1, float* __restrict__ pg2,
            int V, int F, int E, int Ns) {
  __shared__ float red[12];
  const int bid = blockIdx.x;
  const int idx = bid * 256 + threadIdx.x;
  const int VB = V >> 8, FB = F >> 8, EB = E >> 8, SB = Ns >> 8;
  if (bid < VB) {
    int i = idx;
    float dx = deform[3*i], dy = deform[3*i+1], dz = deform[3*i+2];
    float nx = verts[3*i] + dx, ny = verts[3*i+1] + dy, nz = verts[3*i+2] + dz;
    nv[3*i] = nx; nv[3*i+1] = ny; nv[3*i+2] = nz;
    writeRow(rrNf, i, -nx, ny, nz);   // flipped cloud (B-side of sym pass)
    float dot = dx*vnorm[3*i] + dy*vnorm[3*i+1] + dz*vnorm[3*i+2];
    blockRed1(red, fabsf(fminf(dot, -0.1f)), &pg0[bid]);
  } else if (bid < VB + FB) {
    int f = idx - V;
    int i0 = faces[3*f], i1 = faces[3*f+1], i2 = faces[3*f+2];
    float d0x = deform[3*i0], d0y = deform[3*i0+1], d0z = deform[3*i0+2];
    float d1x = deform[3*i1], d1y = deform[3*i1+1], d1z = deform[3*i1+2];
    float d2x = deform[3*i2], d2y = deform[3*i2+1], d2z = deform[3*i2+2];
    float v0x = verts[3*i0]+d0x, v0y = verts[3*i0+1]+d0y, v0z = verts[3*i0+2]+d0z;
    float v1x = verts[3*i1]+d1x, v1y = verts[3*i1+1]+d1y, v1z = verts[3*i1+2]+d1z;
    float v2x = verts[3*i2]+d2x, v2y = verts[3*i2+1]+d2y, v2z = verts[3*i2+2]+d2z;
    float e0 = sqrtf((v0x-v1x)*(v0x-v1x)+(v0y-v1y)*(v0y-v1y)+(v0z-v1z)*(v0z-v1z));
    float e1 = sqrtf((v1x-v2x)*(v1x-v2x)+(v1y-v2y)*(v1y-v2y)+(v1z-v2z)*(v1z-v2z));
    float e2 = sqrtf((v2x-v0x)*(v2x-v0x)+(v2y-v0y)*(v2y-v0y)+(v2z-v0z)*(v2z-v0z));
    e012[f] = e0; e012[F+f] = e1; e012[2*F+f] = e2;
    float ax = v1x-v0x, ay = v1y-v0y, az = v1z-v0z;
    float bx = v2x-v0x, by = v2y-v0y, bz = v2z-v0z;
    float fnx = ay*bz - az*by, fny = az*bx - ax*bz, fnz = ax*by - ay*bx;
    fn_raw[3*f] = fnx; fn_raw[3*f+1] = fny; fn_raw[3*f+2] = fnz;
    float inv = 1.0f / (sqrtf(fnx*fnx+fny*fny+fnz*fnz) + MEPS);
    fn_unit[3*f] = fnx*inv; fn_unit[3*f+1] = fny*inv; fn_unit[3*f+2] = fnz*inv;
    float s0 = sqrtf(d0x*d0x + d0y*d0y + d0z*d0z);
    float s1 = sqrtf(d1x*d1x + d1y*d1y + d1z*d1z);
    float s2 = sqrtf(d2x*d2x + d2y*d2y + d2z*d2z);
    blockRed3(red, e0 + e1 + e2,
              fabsf(e0-e1) + fabsf(e1-e2) + fabsf(e2-e0),
              fabsf(s0-s1) + fabsf(s1-s2) + fabsf(s2-s0),
              &pg0[bid], &pg1[bid], &pg2[bid]);
  } else if (bid < VB + FB + EB) {
    int e = idx - V - F;
    int a = edges[2*e], b = edges[2*e+1];
    float pax = verts[3*a]+deform[3*a], pay = verts[3*a+1]+deform[3*a+1], paz = verts[3*a+2]+deform[3*a+2];
    float pbx = verts[3*b]+deform[3*b], pby = verts[3*b+1]+deform[3*b+1], pbz = verts[3*b+2]+deform[3*b+2];
    elen[e] = sqrtf((pax-pbx)*(pax-pbx)+(pay-pby)*(pay-pby)+(paz-pbz)*(paz-pbz));
  } else if (bid < VB + FB + EB + SB) {
    int s = idx - V - F - E;
    int f = sfi[s];
    int i0 = faces[3*f], i1 = faces[3*f+1], i2 = faces[3*f+2];
    float w0 = bary[3*s], w1 = bary[3*s+1], w2 = bary[3*s+2];
    float sx = w0*(verts[3*i0]  +deform[3*i0])   + w1*(verts[3*i1]  +deform[3*i1])   + w2*(verts[3*i2]  +deform[3*i2]);
    float sy = w0*(verts[3*i0+1]+deform[3*i0+1]) + w1*(verts[3*i1+1]+deform[3*i1+1]) + w2*(verts[3*i2+1]+deform[3*i2+1]);
    float sz = w0*(verts[3*i0+2]+deform[3*i0+2]) + w1*(verts[3*i1+2]+deform[3*i1+2]) + w2*(verts[3*i2+2]+deform[3*i2+2]);
    s_src[3*s] = sx; s_src[3*s+1] = sy; s_src[3*s+2] = sz;
    writeRow(rrS, s, sx, sy, sz);
  } else {
    int t = idx - V - F - E - Ns;
    writeRow(rrT, t, strg[3*t], strg[3*t+1], strg[3*t+2]);
  }
}

// ---- K2: sliced range-gather (4 slices) + fused reduceG tail block (bid 512).
__global__ __launch_bounds__(256)
void k_scatterR(const int* __restrict__ faces, const int* __restrict__ edges,
                const float* __restrict__ fn_raw, const float* __restrict__ nv,
                float* __restrict__ psum,
                const float* __restrict__ pg0, const float* __restrict__ pg1,
                const float* __restrict__ pg2, float* __restrict__ acc,
                int V, int F, int E) {
  const int tid = threadIdx.x;
  const int bid = blockIdx.x;
  if (bid == 512) {  // reduceG
    __shared__ float red[16];
    int wave = tid >> 6, lane = tid & 63;
    const int VB = V >> 8, FB = F >> 8;
    float pen = 0, es = 0, l1 = 0, sm = 0;
    for (int i = tid; i < VB; i += 256) pen += pg0[i];
    for (int i = VB + tid; i < VB + FB; i += 256) { es += pg0[i]; l1 += pg1[i]; sm += pg2[i]; }
    pen = waveReduceAdd(pen); es = waveReduceAdd(es);
    l1 = waveReduceAdd(l1);   sm = waveReduceAdd(sm);
    if (lane == 0) { red[wave] = pen; red[4+wave] = es; red[8+wave] = l1; red[12+wave] = sm; }
    __syncthreads();
    if (tid == 0) {
      acc[11] = red[0]+red[1]+red[2]+red[3];
      acc[0]  = red[4]+red[5]+red[6]+red[7];
      acc[1]  = red[8]+red[9]+red[10]+red[11];
      acc[5]  = red[12]+red[13]+red[14]+red[15];
    }
    return;
  }
  __shared__ float lds[4][256];
#pragma unroll
  for (int c = 0; c < 4; ++c) lds[c][tid] = 0.f;
  __syncthreads();
  if (bid < 256) {
    int r = bid & 63, s = bid >> 6;
    int base = r << 8;
    int fs = F >> 2;
    for (int f = s*fs + tid; f < s*fs + fs; f += 256) {
      int i0 = faces[3*f], i1 = faces[3*f+1], i2 = faces[3*f+2];
      unsigned r0 = (unsigned)(i0-base), r1 = (unsigned)(i1-base), r2 = (unsigned)(i2-base);
      if ((r0 < 256u) | (r1 < 256u) | (r2 < 256u)) {
        float fx = fn_raw[3*f], fy = fn_raw[3*f+1], fz = fn_raw[3*f+2];
        if (r0 < 256u) { atomicAdd(&lds[0][r0],fx); atomicAdd(&lds[1][r0],fy); atomicAdd(&lds[2][r0],fz); }
        if (r1 < 256u) { atomicAdd(&lds[0][r1],fx); atomicAdd(&lds[1][r1],fy); atomicAdd(&lds[2][r1],fz); }
        if (r2 < 256u) { atomicAdd(&lds[0][r2],fx); atomicAdd(&lds[1][r2],fy); atomicAdd(&lds[2][r2],fz); }
      }
    }
    __syncthreads();
#pragma unroll
    for (int c = 0; c < 3; ++c) psum[(size_t)(s*7 + 4 + c)*V + base + tid] = lds[c][tid];
  } else {
    int b2 = bid - 256;
    int r = b2 & 63, s = b2 >> 6;
    int base = r << 8;
    int es = E >> 2;
    for (int e = s*es + tid; e < s*es + es; e += 256) {
      int a = edges[2*e], b = edges[2*e+1];
      unsigned ra = (unsigned)(a-base), rb = (unsigned)(b-base);
      if (ra < 256u) {
        atomicAdd(&lds[0][ra], nv[3*b]); atomicAdd(&lds[1][ra], nv[3*b+1]);
        atomicAdd(&lds[2][ra], nv[3*b+2]); atomicAdd(&lds[3][ra], 1.0f);
      }
      if (rb < 256u) {
        atomicAdd(&lds[0][rb], nv[3*a]); atomicAdd(&lds[1][rb], nv[3*a+1]);
        atomicAdd(&lds[2][rb], nv[3*a+2]); atomicAdd(&lds[3][rb], 1.0f);
      }
    }
    __syncthreads();
#pragma unroll
    for (int c = 0; c < 4; ++c) psum[(size_t)(s*7 + c)*V + base + tid] = lds[c][tid];
  }
}

__device__ __forceinline__ void vfinBody(const float* __restrict__ psum,
                                         const float* __restrict__ nv,
                                         const float* __restrict__ vnorm,
                                         float* red, int v, int V,
                                         float* o0, float* o1) {
  float nbx=0, nby=0, nbz=0, dg=0, vx=0, vy=0, vz=0;
#pragma unroll
  for (int s = 0; s < 4; ++s) {
    nbx += psum[(size_t)(s*7+0)*V + v];
    nby += psum[(size_t)(s*7+1)*V + v];
    nbz += psum[(size_t)(s*7+2)*V + v];
    dg  += psum[(size_t)(s*7+3)*V + v];
    vx  += psum[(size_t)(s*7+4)*V + v];
    vy  += psum[(size_t)(s*7+5)*V + v];
    vz  += psum[(size_t)(s*7+6)*V + v];
  }
  float inv = 1.0f / fmaxf(dg, 1.0f);
  float lx = nbx*inv - nv[3*v];
  float ly = nby*inv - nv[3*v+1];
  float lz = nbz*inv - nv[3*v+2];
  float lap = sqrtf(lx*lx + ly*ly + lz*lz);
  float vinv = 1.0f / (sqrtf(vx*vx + vy*vy + vz*vz) + MEPS);
  float dx = vx*vinv - vnorm[3*v];
  float dy = vy*vinv - vnorm[3*v+1];
  float dz = vz*vinv - vnorm[3*v+2];
  blockRed2(red, lap, dx*dx + dy*dy + dz*dz, o0, o1);
}

__global__ __launch_bounds__(256)
void k_vfinSolo(const float* __restrict__ psum, const float* __restrict__ nv,
                const float* __restrict__ vnorm,
                float* __restrict__ pl0, float* __restrict__ pl1, int V) {
  __shared__ float red[8];
  vfinBody(psum, nv, vnorm, red, blockIdx.x*256 + threadIdx.x, V,
           &pl0[blockIdx.x], &pl1[blockIdx.x]);
}

// left-chained so clang fuses to v_min3_f32
__device__ __forceinline__ float m3(float a, float b, float c) {
  return fminf(fminf(a, b), c);
}
__device__ __forceinline__ float rmin16(float m, f32x16 d) {
  float u0 = m3(d[0],  d[1],  d[2]);
  float u1 = m3(d[3],  d[4],  d[5]);
  float u2 = m3(d[6],  d[7],  d[8]);
  float u3 = m3(d[9],  d[10], d[11]);
  float u4 = m3(d[12], d[13], d[14]);
  float v0 = m3(u0, u1, u2);
  float v1 = m3(u3, u4, d[15]);
  return m3(m, v0, v1);
}

// ---- K3: MFMA chamfer, all three passes in one launch.
// Block = 4 waves x 128 a-cols = 512 a-points; chunk = STAGES x 512 b-records.
// Staging via global_load_lds (async DMA, zero VGPRs) + double-buffered LDS:
// next stage's DMA is issued before the 16-bt compute; the vmcnt(0) drain at
// the single per-stage barrier lands after ~850 cycles of MFMA+min, hiding
// L2 latency. Global source is pre-swizzled (m173) so the linear DMA writes
// reproduce the [half][record] LDS layout; reads identical to R10.
template<int STAGES>
__global__ __launch_bounds__(256, 4)
void k_chamM(const uint4* __restrict__ rrS, const uint4* __restrict__ rrT,
             const uint4* __restrict__ rrNf,
             float* __restrict__ pch1, float* __restrict__ pch2, float* __restrict__ pch3,
             int Ns, int Nt, int V) {
  __shared__ uint4 sB[2][1024];          // 2 x 16 KB: [buf][half*512 + record]
  const int tid = threadIdx.x;
  const int wv = tid >> 6, ln = tid & 63;
  const int col = ln & 31, half = ln >> 5;
  const int shC = (STAGES == 4) ? 11 : 12;   // chunk = STAGES*512
  const int aT1 = Ns >> 9, aT2 = Nt >> 9, aT3 = V >> 9;
  const int nb1 = Nt >> shC, nb2 = Ns >> shC;
  const int B1 = aT1 * nb1, B2 = B1 + aT2 * nb2;
  const int bid = blockIdx.x;
  const uint4 *cr, *rr; float* pch; int at, bc, Na; float sx;
  if (bid < B1)      { cr = rrS;  rr = rrT;  pch = pch1; Na = Ns; at = bid % aT1; bc = bid / aT1; sx = -2.f; }
  else if (bid < B2) { int l = bid - B1; cr = rrT;  rr = rrS;  pch = pch2; Na = Nt; at = l % aT2; bc = l / aT2; sx = -2.f; }
  else               { int l = bid - B2; cr = rrNf; rr = rrNf; pch = pch3; Na = V;  at = l % aT3; bc = l / aT3; sx = 2.f; }
  // sx=+2 for sym pass: rrNf stores -x; col side needs -2*(+x) = +2*(-x).
  const int aBase = (at << 9) + (wv << 7);

  // Build 4 col-frag (B-operand) sets from the col cloud's records.
  bf16x8 bfrag[4];
#pragma unroll
  for (int s = 0; s < 4; ++s) {
    const uint4* crp = cr + ((size_t)(aBase + (s << 5) + col) << 1);
    uint4 q0 = crp[0], q1 = crp[1];
    unsigned short e0 = (unsigned short)(q0.x & 0xFFFFu);
    unsigned short e2 = (unsigned short)(q0.y & 0xFFFFu);
    unsigned short e3 = (unsigned short)(q0.y >> 16);
    unsigned short e5 = (unsigned short)(q0.z >> 16);
    unsigned short e6 = (unsigned short)(q0.w & 0xFFFFu);
    unsigned short e8 = (unsigned short)(q1.x & 0xFFFFu);
    unsigned short a0 = bfr(sx   * bff(e0));   // +-2*hx
    unsigned short a1 = bfr(sx   * bff(e2));   // +-2*lx
    unsigned short a3 = bfr(-2.f * bff(e3));   // -2*hy
    unsigned short a4 = bfr(-2.f * bff(e5));   // -2*ly
    unsigned short a6 = bfr(-2.f * bff(e6));   // -2*hz
    unsigned short a7 = bfr(-2.f * bff(e8));   // -2*lz
    uint4 bb;
    if (half == 0) {           // k0..7
      bb.x = (unsigned)a0 | ((unsigned)a1 << 16);
      bb.y = (unsigned)a0 | ((unsigned)a3 << 16);
      bb.z = (unsigned)a4 | ((unsigned)a3 << 16);
      bb.w = (unsigned)a6 | ((unsigned)a7 << 16);
    } else {                   // k8..15: [-2hz, 1, 1, 0...]
      bb.x = (unsigned)a6 | (0x3F80u << 16);
      bb.y = 0x3F80u;
      bb.z = 0u; bb.w = 0u;
    }
    bfrag[s] = __builtin_bit_cast(bf16x8, bb);
  }

  float m0 = FINF, m1 = FINF, m2 = FINF, m3v = FINF;
  f32x16 zz = {0.f,0.f,0.f,0.f,0.f,0.f,0.f,0.f,0.f,0.f,0.f,0.f,0.f,0.f,0.f,0.f};
  const int bBase = bc << shC;

  // DMA one 512-record stage into sB[buf]. LDS dest is linear in lane order;
  // global source index is the inverse permutation of the [half][record] layout.
  auto stage_dma = [&](int stIdx, int buf) {
    const uint4* src = rr + ((size_t)(bBase + (stIdx << 9)) << 1);
#pragma unroll
    for (int i = 0; i < 4; ++i) {
      int lc = tid + (i << 8);               // lds chunk 0..1023
      int h = lc >> 9, rec = lc & 511;
      load_lds16(src + ((rec << 1) + h), &sB[buf][lc]);
    }
  };

  stage_dma(0, 0);
  __syncthreads();                            // vmcnt(0) drain: buf0 ready
  int cur = 0;
#pragma unroll 1
  for (int st = 0; st < STAGES; ++st) {
    if (st + 1 < STAGES) stage_dma(st + 1, cur ^ 1);   // overlaps with compute
    const bf16x8* lp = (const bf16x8*)&sB[cur][half << 9];
    bf16x8 af = lp[col];
#pragma unroll
    for (int bt = 0; bt < 16; ++bt) {
      bf16x8 curf = af;
      if (bt < 15) af = lp[((bt + 1) << 5) + col];   // prefetch next record-frag
      {
        f32x16 d = __builtin_amdgcn_mfma_f32_32x32x16_bf16(curf, bfrag[0], zz, 0, 0, 0);
        m0 = rmin16(m0, d);
      }
      {
        f32x16 d = __builtin_amdgcn_mfma_f32_32x32x16_bf16(curf, bfrag[1], zz, 0, 0, 0);
        m1 = rmin16(m1, d);
      }
      {
        f32x16 d = __builtin_amdgcn_mfma_f32_32x32x16_bf16(curf, bfrag[2], zz, 0, 0, 0);
        m2 = rmin16(m2, d);
      }
      {
        f32x16 d = __builtin_amdgcn_mfma_f32_32x32x16_bf16(curf, bfrag[3], zz, 0, 0, 0);
        m3v = rmin16(m3v, d);
      }
    }
    __syncthreads();   // vmcnt(0) drain of next-stage DMA (already landed) + reader sync
    cur ^= 1;
  }
  float mm0 = fminf(m0,  __shfl_xor(m0, 32));
  float mm1 = fminf(m1,  __shfl_xor(m1, 32));
  float mm2 = fminf(m2,  __shfl_xor(m2, 32));
  float mm3 = fminf(m3v, __shfl_xor(m3v, 32));
  if (ln < 32) {
    size_t base = (size_t)bc * Na + aBase + col;
    pch[base]      = mm0;
    pch[base + 32] = mm1;
    pch[base + 64] = mm2;
    pch[base + 96] = mm3;
  }
}

// ---- K4: fused finalize: chamfer per-point (a^2 + min over chunks) partials,
// avg-dependent terms, (optionally) vfin.
__global__ __launch_bounds__(256)
void k_fin(const float* __restrict__ pch1, const float* __restrict__ pch2,
           const float* __restrict__ pch3,
           const float* __restrict__ s_src, const float* __restrict__ s_trg,
           const float* __restrict__ nv, float* __restrict__ pc,
           const int* __restrict__ fpairs, const float* __restrict__ fn_unit,
           const float* __restrict__ e012, const float* __restrict__ elen,
           const float* __restrict__ acc, float* __restrict__ pf0,
           const float* __restrict__ psum, const float* __restrict__ vnorm,
           float* __restrict__ pl0, float* __restrict__ pl1,
           int Ns, int Nt, int V, int c1, int c2, int c3,
           int P, int F, int E) {
  __shared__ float red[8];
  const int bid = blockIdx.x;
  const int tid = threadIdx.x;
  const int chamB = (Ns + Nt + V) >> 8;
  const int finB = (P + F + E) >> 8;
  if (bid < chamB) {
    int idx = bid * 256 + tid;
    const float* A; const float* pch; int li, nc, Na;
    if (idx < Ns)           { A = s_src; pch = pch1; li = idx;           nc = c1; Na = Ns; }
    else if (idx < Ns + Nt) { A = s_trg; pch = pch2; li = idx - Ns;      nc = c2; Na = Nt; }
    else                    { A = nv;    pch = pch3; li = idx - Ns - Nt; nc = c3; Na = V; }
    float mn = FINF;
#pragma unroll 4
    for (int c = 0; c < nc; ++c) mn = fminf(mn, pch[(size_t)c * Na + li]);
    float x = A[3*li], y = A[3*li+1], z = A[3*li+2];
    blockRed1(red, x*x + y*y + z*z + mn, &pc[bid]);
  } else if (bid < chamB + finB) {
    int idx = (bid - chamB) * 256 + tid;
    const int PB = P >> 8, FB = F >> 8;
    float avg = acc[0] / (3.0f * (float)F);
    float val;
    if (bid - chamB < PB) {
      int f0 = fpairs[2*idx], f1 = fpairs[2*idx+1];
      val = 1.0f - (fn_unit[3*f0]*fn_unit[3*f1] + fn_unit[3*f0+1]*fn_unit[3*f1+1]
                  + fn_unit[3*f0+2]*fn_unit[3*f1+2]);
    } else if (bid - chamB < PB + FB) {
      int f = idx - P;
      val = fabsf(e012[f]-avg) + fabsf(e012[F+f]-avg) + fabsf(e012[2*F+f]-avg);
    } else {
      float d = elen[idx - P - F] - avg;
      val = d * d;
    }
    blockRed1(red, val, &pf0[bid - chamB]);
  } else {
    int vb = bid - chamB - finB;
    vfinBody(psum, nv, vnorm, red, vb*256 + tid, V, &pl0[vb], &pl1[vb]);
  }
}

// ---- K5: final combine (1 block)
__global__ void k_combine(const float* __restrict__ pf0, const float* __restrict__ pl0,
                          const float* __restrict__ pl1, const float* __restrict__ pc,
                          const float* __restrict__ acc, float* __restrict__ out,
                          int V, int F, int E, int P, int Ns, int Nt) {
  __shared__ float red[8][4];
  int tid = threadIdx.x, wave = tid >> 6, lane = tid & 63;
  const int PB = P >> 8, FB = F >> 8, EB = E >> 8, VB = V >> 8, NsB = Ns >> 8, NtB = Nt >> 8;
  float s0=0,s1=0,s2=0,s3=0,s4=0,s5=0,s6=0,s7=0;
  for (int i = tid; i < PB; i += 256) s0 += pf0[i];
  for (int i = tid; i < FB; i += 256) s1 += pf0[PB + i];
  for (int i = tid; i < EB; i += 256) s2 += pf0[PB + FB + i];
  for (int i = tid; i < VB; i += 256) { s3 += pl0[i]; s4 += pl1[i]; }
  for (int i = tid; i < NsB; i += 256) s5 += pc[i];
  for (int i = tid; i < NtB; i += 256) s6 += pc[NsB + i];
  for (int i = tid; i < VB; i += 256) s7 += pc[NsB + NtB + i];
  s0=waveReduceAdd(s0); s1=waveReduceAdd(s1); s2=waveReduceAdd(s2); s3=waveReduceAdd(s3);
  s4=waveReduceAdd(s4); s5=waveReduceAdd(s5); s6=waveReduceAdd(s6); s7=waveReduceAdd(s7);
  if (lane == 0) { red[0][wave]=s0; red[1][wave]=s1; red[2][wave]=s2; red[3][wave]=s3;
                   red[4][wave]=s4; red[5][wave]=s5; red[6][wave]=s6; red[7][wave]=s7; }
  __syncthreads();
  if (tid == 0) {
    float t[8];
#pragma unroll
    for (int c = 0; c < 8; ++c) t[c] = red[c][0]+red[c][1]+red[c][2]+red[c][3];
    float loss = t[5]/(float)Ns + t[6]/(float)Nt;         // chamfer
    loss += 0.1f * ((acc[1] + t[1]) / (float)F);          // face
    loss += 0.1f * (t[2] / (float)E);                     // edge
    loss += 0.1f * (t[0] / (float)P);                     // normal
    loss += 0.1f * (acc[5] / (float)F);                   // smooth
    loss += 0.1f * (t[3] / (float)V);                     // laplacian
    loss += 0.5f * (t[4] / (3.0f * (float)V));            // consistency
    loss += 0.1f * (2.0f * t[7] / (float)V);              // symmetry (flip isometry)
    loss += 5.0f * (acc[11] / (float)V);                  // penetration
    out[0] = loss;
  }
}

extern "C" void kernel_launch(void* const* d_in, const int* in_sizes, int n_in,
                              void* d_out, int out_size, void* d_ws, size_t ws_size,
                              hipStream_t stream) {
  const float* verts   = (const float*)d_in[0];
  const float* deform  = (const float*)d_in[1];
  const float* bary    = (const float*)d_in[2];
  const float* s_trg   = (const float*)d_in[3];
  const float* vnorm   = (const float*)d_in[4];
  const int*   faces   = (const int*)d_in[5];
  const int*   edges   = (const int*)d_in[6];
  const int*   fpairs  = (const int*)d_in[7];
  const int*   sfi     = (const int*)d_in[8];
  float* out = (float*)d_out;

  const int V  = in_sizes[0] / 3;
  const int Ns = in_sizes[2] / 3;
  const int Nt = in_sizes[3] / 3;
  const int F  = in_sizes[5] / 3;
  const int E  = in_sizes[6] / 2;
  const int P  = in_sizes[7] / 2;

  float* ws   = (float*)d_ws;
  float* acc  = ws;                                   // 16
  float* pg0  = ws + 16;                              // 256
  float* pg1  = pg0 + 256;                            // 256
  float* pg2  = pg1 + 256;                            // 256
  float* pf0  = pg2 + 256;                            // 512
  float* pl0  = pf0 + 512;                            // 64
  float* pl1  = pl0 + 64;                             // 64
  float* pc   = pl1 + 64;                             // 256
  float* nv    = pc + 256;                            // 3V
  float* s_src = nv + 3*V;                            // 3Ns
  float* fn_u  = s_src + 3*Ns;                        // 3F
  float* fn_r  = fn_u + 3*F;                          // 3F
  float* e012  = fn_r + 3*F;                          // 3F
  float* elen  = e012 + 3*F;                          // E
  float* psum  = elen + E;                            // 28V
  float* recF  = psum + 28*V;                         // 8*(Ns+Nt+V)
  uint4* rrS  = (uint4*)recF;
  uint4* rrT  = (uint4*)(recF + 8*Ns);
  uint4* rrNf = (uint4*)(recF + 8*Ns + 8*Nt);

  size_t fixedEnd = (size_t)(recF - ws) + 8*(size_t)(Ns + Nt + V);
  size_t wsFloats = ws_size / sizeof(float);
  // config A: 2048-b chunks (STAGES=4) disjoint; B: 4096 (STAGES=8) disjoint; C: 4096 aliased
  int nb1_2 = Nt >> 11, nb2_2 = Ns >> 11, nb3_2 = V >> 11;
  int nb1_4 = Nt >> 12, nb2_4 = Ns >> 12, nb3_4 = V >> 12;
  size_t pch2F = (size_t)nb1_2*Ns + (size_t)nb2_2*Nt + (size_t)nb3_2*V;
  size_t pch4F = (size_t)nb1_4*Ns + (size_t)nb2_4*Nt + (size_t)nb3_4*V;
  int stages; bool disjoint;
  int nb1, nb2, nb3;
  if (fixedEnd + pch2F <= wsFloats)      { stages = 4; disjoint = true;  nb1=nb1_2; nb2=nb2_2; nb3=nb3_2; }
  else if (fixedEnd + pch4F <= wsFloats) { stages = 8; disjoint = true;  nb1=nb1_4; nb2=nb2_4; nb3=nb3_4; }
  else                                   { stages = 8; disjoint = false; nb1=nb1_4; nb2=nb2_4; nb3=nb3_4; }
  float* pchBase = disjoint ? (recF + 8*(Ns + Nt + V)) : psum;
  float* pch1 = pchBase;
  float* pch2 = pch1 + (size_t)nb1 * Ns;
  float* pch3 = pch2 + (size_t)nb2 * Nt;

  int nGeom = (V + F + E + Ns + Nt) / 256;
  k_geom<<<nGeom, 256, 0, stream>>>(verts, deform, vnorm, bary, faces, edges, sfi,
                                    s_trg, nv, s_src, e012, fn_u, fn_r, elen,
                                    rrS, rrT, rrNf, pg0, pg1, pg2, V, F, E, Ns);
  k_scatterR<<<513, 256, 0, stream>>>(faces, edges, fn_r, nv, psum,
                                      pg0, pg1, pg2, acc, V, F, E);
  if (!disjoint)   // pch will overwrite psum -> finish laplacian/consistency first
    k_vfinSolo<<<V/256, 256, 0, stream>>>(psum, nv, vnorm, pl0, pl1, V);

  int nCham = (Ns >> 9) * nb1 + (Nt >> 9) * nb2 + (V >> 9) * nb3;
  if (stages == 4)
    k_chamM<4><<<nCham, 256, 0, stream>>>(rrS, rrT, rrNf, pch1, pch2, pch3, Ns, Nt, V);
  else
    k_chamM<8><<<nCham, 256, 0, stream>>>(rrS, rrT, rrNf, pch1, pch2, pch3, Ns, Nt, V);

  int chamB = (Ns + Nt + V) >> 8, finB = (P + F + E) >> 8;
  int vfinB = disjoint ? (V >> 8) : 0;
  k_fin<<<chamB + finB + vfinB, 256, 0, stream>>>(pch1, pch2, pch3, s_src, s_trg, nv, pc,
                                                  fpairs, fn_u, e012, elen, acc, pf0,
                                                  psum, vnorm, pl0, pl1,
                                                  Ns, Nt, V, nb1, nb2, nb3, P, F, E);
  k_combine<<<1, 256, 0, stream>>>(pf0, pl0, pl1, pc, acc, out, V, F, E, P, Ns, Nt);
}

// Round 13
// 82.021 us; speedup vs baseline: 1.1559x; 1.0412x over previous
//
#include <hip/hip_runtime.h>

#define MEPS 1e-6f
#define FINF 3.402823466e38f

typedef short bf16x8 __attribute__((ext_vector_type(8)));   // 8 bf16 (4 VGPRs)
typedef float f32x16 __attribute__((ext_vector_type(16)));  // MFMA 32x32 C/D

// async 16B global->LDS DMA (no VGPR round-trip)
__device__ __forceinline__ void load_lds16(const uint4* g, uint4* l) {
  __builtin_amdgcn_global_load_lds(
      (const __attribute__((address_space(1))) unsigned int*)g,
      (__attribute__((address_space(3))) unsigned int*)l, 16, 0, 0);
}

// bf16 round-to-nearest-even
__device__ __forceinline__ unsigned short bfr(float f) {
  unsigned u = __float_as_uint(f);
  return (unsigned short)((u + 0x7FFFu + ((u >> 16) & 1u)) >> 16);
}
__device__ __forceinline__ float bff(unsigned short h) {
  return __uint_as_float(((unsigned)h) << 16);
}
// Row-record (MFMA A-operand, b-points), 16 bf16 = 32B
__device__ __forceinline__ void writeRow(uint4* __restrict__ dst, int i,
                                         float x, float y, float z) {
  unsigned short hx = bfr(x); float fhx = bff(hx); unsigned short lx = bfr(x - fhx);
  unsigned short hy = bfr(y); float fhy = bff(hy); unsigned short ly = bfr(y - fhy);
  unsigned short hz = bfr(z); float fhz = bff(hz); unsigned short lz = bfr(z - fhz);
  float s = fmaf(x, x, fmaf(y, y, z * z));
  unsigned short hs = bfr(s); unsigned short ls = bfr(s - bff(hs));
  uint4 r0, r1;
  r0.x = (unsigned)hx | ((unsigned)hx << 16);
  r0.y = (unsigned)lx | ((unsigned)hy << 16);
  r0.z = (unsigned)hy | ((unsigned)ly << 16);
  r0.w = (unsigned)hz | ((unsigned)hz << 16);
  r1.x = (unsigned)lz | ((unsigned)hs << 16);
  r1.y = (unsigned)ls;
  r1.z = 0u; r1.w = 0u;
  dst[2*i] = r0; dst[2*i+1] = r1;
}

__device__ __forceinline__ float waveReduceAdd(float v) {
#pragma unroll
  for (int off = 32; off > 0; off >>= 1) v += __shfl_down(v, off, 64);
  return v;
}
__device__ __forceinline__ void blockRed1(float* red, float v, float* out) {
  int wave = threadIdx.x >> 6, lane = threadIdx.x & 63;
  v = waveReduceAdd(v);
  if (lane == 0) red[wave] = v;
  __syncthreads();
  if (threadIdx.x == 0) out[0] = red[0] + red[1] + red[2] + red[3];
}
__device__ __forceinline__ void blockRed2(float* red, float v0, float v1,
                                          float* o0, float* o1) {
  int wave = threadIdx.x >> 6, lane = threadIdx.x & 63;
  v0 = waveReduceAdd(v0); v1 = waveReduceAdd(v1);
  if (lane == 0) { red[wave] = v0; red[4 + wave] = v1; }
  __syncthreads();
  if (threadIdx.x == 0) {
    o0[0] = red[0] + red[1] + red[2] + red[3];
    o1[0] = red[4] + red[5] + red[6] + red[7];
  }
}
__device__ __forceinline__ void blockRed3(float* red, float v0, float v1, float v2,
                                          float* o0, float* o1, float* o2) {
  int wave = threadIdx.x >> 6, lane = threadIdx.x & 63;
  v0 = waveReduceAdd(v0); v1 = waveReduceAdd(v1); v2 = waveReduceAdd(v2);
  if (lane == 0) { red[wave] = v0; red[4 + wave] = v1; red[8 + wave] = v2; }
  __syncthreads();
  if (threadIdx.x == 0) {
    o0[0] = red[0] + red[1] + red[2] + red[3];
    o1[0] = red[4] + red[5] + red[6] + red[7];
    o2[0] = red[8] + red[9] + red[10] + red[11];
  }
}

// ---- K1: fused streaming pass + bf16 record emission. Branch uniform per block.
__global__ __launch_bounds__(256)
void k_geom(const float* __restrict__ verts, const float* __restrict__ deform,
            const float* __restrict__ vnorm, const float* __restrict__ bary,
            const int* __restrict__ faces, const int* __restrict__ edges,
            const int* __restrict__ sfi, const float* __restrict__ strg,
            float* __restrict__ nv, float* __restrict__ s_src,
            float* __restrict__ e012, float* __restrict__ fn_unit,
            float* __restrict__ fn_raw, float* __restrict__ elen,
            uint4* __restrict__ rrS, uint4* __restrict__ rrT, uint4* __restrict__ rrNf,
            float* __restrict__ pg0, float* __restrict__ pg1, float* __restrict__ pg2,
            int V, int F, int E, int Ns) {
  __shared__ float red[12];
  const int bid = blockIdx.x;
  const int idx = bid * 256 + threadIdx.x;
  const int VB = V >> 8, FB = F >> 8, EB = E >> 8, SB = Ns >> 8;
  if (bid < VB) {
    int i = idx;
    float dx = deform[3*i], dy = deform[3*i+1], dz = deform[3*i+2];
    float nx = verts[3*i] + dx, ny = verts[3*i+1] + dy, nz = verts[3*i+2] + dz;
    nv[3*i] = nx; nv[3*i+1] = ny; nv[3*i+2] = nz;
    writeRow(rrNf, i, -nx, ny, nz);   // flipped cloud (B-side of sym pass)
    float dot = dx*vnorm[3*i] + dy*vnorm[3*i+1] + dz*vnorm[3*i+2];
    blockRed1(red, fabsf(fminf(dot, -0.1f)), &pg0[bid]);
  } else if (bid < VB + FB) {
    int f = idx - V;
    int i0 = faces[3*f], i1 = faces[3*f+1], i2 = faces[3*f+2];
    float d0x = deform[3*i0], d0y = deform[3*i0+1], d0z = deform[3*i0+2];
    float d1x = deform[3*i1], d1y = deform[3*i1+1], d1z = deform[3*i1+2];
    float d2x = deform[3*i2], d2y = deform[3*i2+1], d2z = deform[3*i2+2];
    float v0x = verts[3*i0]+d0x, v0y = verts[3*i0+1]+d0y, v0z = verts[3*i0+2]+d0z;
    float v1x = verts[3*i1]+d1x, v1y = verts[3*i1+1]+d1y, v1z = verts[3*i1+2]+d1z;
    float v2x = verts[3*i2]+d2x, v2y = verts[3*i2+1]+d2y, v2z = verts[3*i2+2]+d2z;
    float e0 = sqrtf((v0x-v1x)*(v0x-v1x)+(v0y-v1y)*(v0y-v1y)+(v0z-v1z)*(v0z-v1z));
    float e1 = sqrtf((v1x-v2x)*(v1x-v2x)+(v1y-v2y)*(v1y-v2y)+(v1z-v2z)*(v1z-v2z));
    float e2 = sqrtf((v2x-v0x)*(v2x-v0x)+(v2y-v0y)*(v2y-v0y)+(v2z-v0z)*(v2z-v0z));
    e012[f] = e0; e012[F+f] = e1; e012[2*F+f] = e2;
    float ax = v1x-v0x, ay = v1y-v0y, az = v1z-v0z;
    float bx = v2x-v0x, by = v2y-v0y, bz = v2z-v0z;
    float fnx = ay*bz - az*by, fny = az*bx - ax*bz, fnz = ax*by - ay*bx;
    fn_raw[3*f] = fnx; fn_raw[3*f+1] = fny; fn_raw[3*f+2] = fnz;
    float inv = 1.0f / (sqrtf(fnx*fnx+fny*fny+fnz*fnz) + MEPS);
    fn_unit[3*f] = fnx*inv; fn_unit[3*f+1] = fny*inv; fn_unit[3*f+2] = fnz*inv;
    float s0 = sqrtf(d0x*d0x + d0y*d0y + d0z*d0z);
    float s1 = sqrtf(d1x*d1x + d1y*d1y + d1z*d1z);
    float s2 = sqrtf(d2x*d2x + d2y*d2y + d2z*d2z);
    blockRed3(red, e0 + e1 + e2,
              fabsf(e0-e1) + fabsf(e1-e2) + fabsf(e2-e0),
              fabsf(s0-s1) + fabsf(s1-s2) + fabsf(s2-s0),
              &pg0[bid], &pg1[bid], &pg2[bid]);
  } else if (bid < VB + FB + EB) {
    int e = idx - V - F;
    int a = edges[2*e], b = edges[2*e+1];
    float pax = verts[3*a]+deform[3*a], pay = verts[3*a+1]+deform[3*a+1], paz = verts[3*a+2]+deform[3*a+2];
    float pbx = verts[3*b]+deform[3*b], pby = verts[3*b+1]+deform[3*b+1], pbz = verts[3*b+2]+deform[3*b+2];
    elen[e] = sqrtf((pax-pbx)*(pax-pbx)+(pay-pby)*(pay-pby)+(paz-pbz)*(paz-pbz));
  } else if (bid < VB + FB + EB + SB) {
    int s = idx - V - F - E;
    int f = sfi[s];
    int i0 = faces[3*f], i1 = faces[3*f+1], i2 = faces[3*f+2];
    float w0 = bary[3*s], w1 = bary[3*s+1], w2 = bary[3*s+2];
    float sx = w0*(verts[3*i0]  +deform[3*i0])   + w1*(verts[3*i1]  +deform[3*i1])   + w2*(verts[3*i2]  +deform[3*i2]);
    float sy = w0*(verts[3*i0+1]+deform[3*i0+1]) + w1*(verts[3*i1+1]+deform[3*i1+1]) + w2*(verts[3*i2+1]+deform[3*i2+1]);
    float sz = w0*(verts[3*i0+2]+deform[3*i0+2]) + w1*(verts[3*i1+2]+deform[3*i1+2]) + w2*(verts[3*i2+2]+deform[3*i2+2]);
    s_src[3*s] = sx; s_src[3*s+1] = sy; s_src[3*s+2] = sz;
    writeRow(rrS, s, sx, sy, sz);
  } else {
    int t = idx - V - F - E - Ns;
    writeRow(rrT, t, strg[3*t], strg[3*t+1], strg[3*t+2]);
  }
}

// scatter body (works on an aliased LDS region of >=4KB) — 512 blocks + reduceG.
__device__ __forceinline__ void scatterBody(
    int sb, int tid, float* ldsF,
    const int* __restrict__ faces, const int* __restrict__ edges,
    const float* __restrict__ fn_raw, const float* __restrict__ nv,
    float* __restrict__ psum,
    const float* __restrict__ pg0, const float* __restrict__ pg1,
    const float* __restrict__ pg2, float* __restrict__ acc,
    int V, int F, int E) {
  if (sb == 512) {  // reduceG
    float* red = ldsF;
    int wave = tid >> 6, lane = tid & 63;
    const int VB = V >> 8, FB = F >> 8;
    float pen = 0, es = 0, l1 = 0, sm = 0;
    for (int i = tid; i < VB; i += 256) pen += pg0[i];
    for (int i = VB + tid; i < VB + FB; i += 256) { es += pg0[i]; l1 += pg1[i]; sm += pg2[i]; }
    pen = waveReduceAdd(pen); es = waveReduceAdd(es);
    l1 = waveReduceAdd(l1);   sm = waveReduceAdd(sm);
    if (lane == 0) { red[wave] = pen; red[4+wave] = es; red[8+wave] = l1; red[12+wave] = sm; }
    __syncthreads();
    if (tid == 0) {
      acc[11] = red[0]+red[1]+red[2]+red[3];
      acc[0]  = red[4]+red[5]+red[6]+red[7];
      acc[1]  = red[8]+red[9]+red[10]+red[11];
      acc[5]  = red[12]+red[13]+red[14]+red[15];
    }
    return;
  }
  float* lds = ldsF;   // [4][256] aliased
#pragma unroll
  for (int c = 0; c < 4; ++c) lds[c*256 + tid] = 0.f;
  __syncthreads();
  if (sb < 256) {
    int r = sb & 63, s = sb >> 6;
    int base = r << 8;
    int fs = F >> 2;
    for (int f = s*fs + tid; f < s*fs + fs; f += 256) {
      int i0 = faces[3*f], i1 = faces[3*f+1], i2 = faces[3*f+2];
      unsigned r0 = (unsigned)(i0-base), r1 = (unsigned)(i1-base), r2 = (unsigned)(i2-base);
      if ((r0 < 256u) | (r1 < 256u) | (r2 < 256u)) {
        float fx = fn_raw[3*f], fy = fn_raw[3*f+1], fz = fn_raw[3*f+2];
        if (r0 < 256u) { atomicAdd(&lds[r0],fx); atomicAdd(&lds[256+r1*0+r0],fy); atomicAdd(&lds[512+r0],fz); }
        if (r1 < 256u) { atomicAdd(&lds[r1],fx); atomicAdd(&lds[256+r1],fy); atomicAdd(&lds[512+r1],fz); }
        if (r2 < 256u) { atomicAdd(&lds[r2],fx); atomicAdd(&lds[256+r2],fy); atomicAdd(&lds[512+r2],fz); }
      }
    }
    __syncthreads();
#pragma unroll
    for (int c = 0; c < 3; ++c) psum[(size_t)(s*7 + 4 + c)*V + base + tid] = lds[c*256 + tid];
  } else {
    int b2 = sb - 256;
    int r = b2 & 63, s = b2 >> 6;
    int base = r << 8;
    int es = E >> 2;
    for (int e = s*es + tid; e < s*es + es; e += 256) {
      int a = edges[2*e], b = edges[2*e+1];
      unsigned ra = (unsigned)(a-base), rb = (unsigned)(b-base);
      if (ra < 256u) {
        atomicAdd(&lds[ra], nv[3*b]); atomicAdd(&lds[256+ra], nv[3*b+1]);
        atomicAdd(&lds[512+ra], nv[3*b+2]); atomicAdd(&lds[768+ra], 1.0f);
      }
      if (rb < 256u) {
        atomicAdd(&lds[rb], nv[3*a]); atomicAdd(&lds[256+rb], nv[3*a+1]);
        atomicAdd(&lds[512+rb], nv[3*a+2]); atomicAdd(&lds[768+rb], 1.0f);
      }
    }
    __syncthreads();
#pragma unroll
    for (int c = 0; c < 4; ++c) psum[(size_t)(s*7 + c)*V + base + tid] = lds[c*256 + tid];
  }
}

// standalone scatter (aliased-ws fallback only)
__global__ __launch_bounds__(256)
void k_scatterR(const int* __restrict__ faces, const int* __restrict__ edges,
                const float* __restrict__ fn_raw, const float* __restrict__ nv,
                float* __restrict__ psum,
                const float* __restrict__ pg0, const float* __restrict__ pg1,
                const float* __restrict__ pg2, float* __restrict__ acc,
                int V, int F, int E) {
  __shared__ float lds[1024];
  scatterBody(blockIdx.x, threadIdx.x, lds, faces, edges, fn_raw, nv, psum,
              pg0, pg1, pg2, acc, V, F, E);
}

__device__ __forceinline__ void vfinBody(const float* __restrict__ psum,
                                         const float* __restrict__ nv,
                                         const float* __restrict__ vnorm,
                                         float* red, int v, int V,
                                         float* o0, float* o1) {
  float nbx=0, nby=0, nbz=0, dg=0, vx=0, vy=0, vz=0;
#pragma unroll
  for (int s = 0; s < 4; ++s) {
    nbx += psum[(size_t)(s*7+0)*V + v];
    nby += psum[(size_t)(s*7+1)*V + v];
    nbz += psum[(size_t)(s*7+2)*V + v];
    dg  += psum[(size_t)(s*7+3)*V + v];
    vx  += psum[(size_t)(s*7+4)*V + v];
    vy  += psum[(size_t)(s*7+5)*V + v];
    vz  += psum[(size_t)(s*7+6)*V + v];
  }
  float inv = 1.0f / fmaxf(dg, 1.0f);
  float lx = nbx*inv - nv[3*v];
  float ly = nby*inv - nv[3*v+1];
  float lz = nbz*inv - nv[3*v+2];
  float lap = sqrtf(lx*lx + ly*ly + lz*lz);
  float vinv = 1.0f / (sqrtf(vx*vx + vy*vy + vz*vz) + MEPS);
  float dx = vx*vinv - vnorm[3*v];
  float dy = vy*vinv - vnorm[3*v+1];
  float dz = vz*vinv - vnorm[3*v+2];
  blockRed2(red, lap, dx*dx + dy*dy + dz*dz, o0, o1);
}

__global__ __launch_bounds__(256)
void k_vfinSolo(const float* __restrict__ psum, const float* __restrict__ nv,
                const float* __restrict__ vnorm,
                float* __restrict__ pl0, float* __restrict__ pl1, int V) {
  __shared__ float red[8];
  vfinBody(psum, nv, vnorm, red, blockIdx.x*256 + threadIdx.x, V,
           &pl0[blockIdx.x], &pl1[blockIdx.x]);
}

// left-chained so clang fuses to v_min3_f32
__device__ __forceinline__ float m3(float a, float b, float c) {
  return fminf(fminf(a, b), c);
}
__device__ __forceinline__ float rmin16(float m, f32x16 d) {
  float u0 = m3(d[0],  d[1],  d[2]);
  float u1 = m3(d[3],  d[4],  d[5]);
  float u2 = m3(d[6],  d[7],  d[8]);
  float u3 = m3(d[9],  d[10], d[11]);
  float u4 = m3(d[12], d[13], d[14]);
  float v0 = m3(u0, u1, u2);
  float v1 = m3(u3, u4, d[15]);
  return m3(m, v0, v1);
}

// ---- K3: MEGA kernel: MFMA chamfer (blocks < nCham) + scatter (next 512) +
// reduceG (last block). Chamfer: 4 waves x 128 a-cols; chunk = STAGES x 512
// b-records; DMA double-buffered staging overlapped with compute.
template<int STAGES>
__global__ __launch_bounds__(256, 4)
void k_mega(const uint4* __restrict__ rrS, const uint4* __restrict__ rrT,
            const uint4* __restrict__ rrNf,
            float* __restrict__ pch1, float* __restrict__ pch2, float* __restrict__ pch3,
            const int* __restrict__ faces, const int* __restrict__ edges,
            const float* __restrict__ fn_raw, const float* __restrict__ nv,
            float* __restrict__ psum,
            const float* __restrict__ pg0, const float* __restrict__ pg1,
            const float* __restrict__ pg2, float* __restrict__ acc,
            int Ns, int Nt, int V, int F, int E, int nCham) {
  __shared__ uint4 sB[2][1024];          // 32 KB; scatter/reduceG alias onto it
  const int tid = threadIdx.x;
  const int bid = blockIdx.x;
  if (bid >= nCham) {
    scatterBody(bid - nCham, tid, (float*)sB, faces, edges, fn_raw, nv, psum,
                pg0, pg1, pg2, acc, V, F, E);
    return;
  }
  const int ln = tid & 63, wv = tid >> 6;
  const int col = ln & 31, half = ln >> 5;
  const int shC = (STAGES == 2) ? 10 : ((STAGES == 4) ? 11 : 12);
  const int aT1 = Ns >> 9, aT2 = Nt >> 9, aT3 = V >> 9;
  const int nb1 = Nt >> shC, nb2 = Ns >> shC;
  const int B1 = aT1 * nb1, B2 = B1 + aT2 * nb2;
  const uint4 *cr, *rr; float* pch; int at, bc, Na; float sx;
  if (bid < B1)      { cr = rrS;  rr = rrT;  pch = pch1; Na = Ns; at = bid % aT1; bc = bid / aT1; sx = -2.f; }
  else if (bid < B2) { int l = bid - B1; cr = rrT;  rr = rrS;  pch = pch2; Na = Nt; at = l % aT2; bc = l / aT2; sx = -2.f; }
  else               { int l = bid - B2; cr = rrNf; rr = rrNf; pch = pch3; Na = V;  at = l % aT3; bc = l / aT3; sx = 2.f; }
  // sx=+2 for sym pass: rrNf stores -x; col side needs -2*(+x) = +2*(-x).
  const int aBase = (at << 9) + (wv << 7);

  // Build 4 col-frag (B-operand) sets from the col cloud's records.
  bf16x8 bfrag[4];
#pragma unroll
  for (int s = 0; s < 4; ++s) {
    const uint4* crp = cr + ((size_t)(aBase + (s << 5) + col) << 1);
    uint4 q0 = crp[0], q1 = crp[1];
    unsigned short e0 = (unsigned short)(q0.x & 0xFFFFu);
    unsigned short e2 = (unsigned short)(q0.y & 0xFFFFu);
    unsigned short e3 = (unsigned short)(q0.y >> 16);
    unsigned short e5 = (unsigned short)(q0.z >> 16);
    unsigned short e6 = (unsigned short)(q0.w & 0xFFFFu);
    unsigned short e8 = (unsigned short)(q1.x & 0xFFFFu);
    unsigned short a0 = bfr(sx   * bff(e0));   // +-2*hx
    unsigned short a1 = bfr(sx   * bff(e2));   // +-2*lx
    unsigned short a3 = bfr(-2.f * bff(e3));   // -2*hy
    unsigned short a4 = bfr(-2.f * bff(e5));   // -2*ly
    unsigned short a6 = bfr(-2.f * bff(e6));   // -2*hz
    unsigned short a7 = bfr(-2.f * bff(e8));   // -2*lz
    uint4 bb;
    if (half == 0) {           // k0..7
      bb.x = (unsigned)a0 | ((unsigned)a1 << 16);
      bb.y = (unsigned)a0 | ((unsigned)a3 << 16);
      bb.z = (unsigned)a4 | ((unsigned)a3 << 16);
      bb.w = (unsigned)a6 | ((unsigned)a7 << 16);
    } else {                   // k8..15: [-2hz, 1, 1, 0...]
      bb.x = (unsigned)a6 | (0x3F80u << 16);
      bb.y = 0x3F80u;
      bb.z = 0u; bb.w = 0u;
    }
    bfrag[s] = __builtin_bit_cast(bf16x8, bb);
  }

  float m0 = FINF, m1 = FINF, m2 = FINF, m3v = FINF;
  f32x16 zz = {0.f,0.f,0.f,0.f,0.f,0.f,0.f,0.f,0.f,0.f,0.f,0.f,0.f,0.f,0.f,0.f};
  const int bBase = bc << shC;

  auto stage_dma = [&](int stIdx, int buf) {
    const uint4* src = rr + ((size_t)(bBase + (stIdx << 9)) << 1);
#pragma unroll
    for (int i = 0; i < 4; ++i) {
      int lc = tid + (i << 8);               // lds chunk 0..1023
      int h = lc >> 9, rec = lc & 511;
      load_lds16(src + ((rec << 1) + h), &sB[buf][lc]);
    }
  };

  stage_dma(0, 0);
  __syncthreads();                            // vmcnt(0) drain: buf0 ready
  int cur = 0;
#pragma unroll 1
  for (int st = 0; st < STAGES; ++st) {
    if (st + 1 < STAGES) stage_dma(st + 1, cur ^ 1);   // overlaps with compute
    const bf16x8* lp = (const bf16x8*)&sB[cur][half << 9];
    bf16x8 af = lp[col];
#pragma unroll
    for (int bt = 0; bt < 16; ++bt) {
      bf16x8 curf = af;
      if (bt < 15) af = lp[((bt + 1) << 5) + col];   // prefetch next record-frag
      {
        f32x16 d = __builtin_amdgcn_mfma_f32_32x32x16_bf16(curf, bfrag[0], zz, 0, 0, 0);
        m0 = rmin16(m0, d);
      }
      {
        f32x16 d = __builtin_amdgcn_mfma_f32_32x32x16_bf16(curf, bfrag[1], zz, 0, 0, 0);
        m1 = rmin16(m1, d);
      }
      {
        f32x16 d = __builtin_amdgcn_mfma_f32_32x32x16_bf16(curf, bfrag[2], zz, 0, 0, 0);
        m2 = rmin16(m2, d);
      }
      {
        f32x16 d = __builtin_amdgcn_mfma_f32_32x32x16_bf16(curf, bfrag[3], zz, 0, 0, 0);
        m3v = rmin16(m3v, d);
      }
    }
    __syncthreads();   // drains next-stage DMA (already landed) + reader sync
    cur ^= 1;
  }
  float mm0 = fminf(m0,  __shfl_xor(m0, 32));
  float mm1 = fminf(m1,  __shfl_xor(m1, 32));
  float mm2 = fminf(m2,  __shfl_xor(m2, 32));
  float mm3 = fminf(m3v, __shfl_xor(m3v, 32));
  if (ln < 32) {
    size_t base = (size_t)bc * Na + aBase + col;
    pch[base]      = mm0;
    pch[base + 32] = mm1;
    pch[base + 64] = mm2;
    pch[base + 96] = mm3;
  }
}

// ---- K4: fused finalize: chamfer per-point partials, avg terms, (opt) vfin.
__global__ __launch_bounds__(256)
void k_fin(const float* __restrict__ pch1, const float* __restrict__ pch2,
           const float* __restrict__ pch3,
           const float* __restrict__ s_src, const float* __restrict__ s_trg,
           const float* __restrict__ nv, float* __restrict__ pc,
           const int* __restrict__ fpairs, const float* __restrict__ fn_unit,
           const float* __restrict__ e012, const float* __restrict__ elen,
           const float* __restrict__ acc, float* __restrict__ pf0,
           const float* __restrict__ psum, const float* __restrict__ vnorm,
           float* __restrict__ pl0, float* __restrict__ pl1,
           int Ns, int Nt, int V, int c1, int c2, int c3,
           int P, int F, int E) {
  __shared__ float red[8];
  const int bid = blockIdx.x;
  const int tid = threadIdx.x;
  const int chamB = (Ns + Nt + V) >> 8;
  const int finB = (P + F + E) >> 8;
  if (bid < chamB) {
    int idx = bid * 256 + tid;
    const float* A; const float* pch; int li, nc, Na;
    if (idx < Ns)           { A = s_src; pch = pch1; li = idx;           nc = c1; Na = Ns; }
    else if (idx < Ns + Nt) { A = s_trg; pch = pch2; li = idx - Ns;      nc = c2; Na = Nt; }
    else                    { A = nv;    pch = pch3; li = idx - Ns - Nt; nc = c3; Na = V; }
    float mn = FINF;
#pragma unroll 4
    for (int c = 0; c < nc; ++c) mn = fminf(mn, pch[(size_t)c * Na + li]);
    float x = A[3*li], y = A[3*li+1], z = A[3*li+2];
    blockRed1(red, x*x + y*y + z*z + mn, &pc[bid]);
  } else if (bid < chamB + finB) {
    int idx = (bid - chamB) * 256 + tid;
    const int PB = P >> 8, FB = F >> 8;
    float avg = acc[0] / (3.0f * (float)F);
    float val;
    if (bid - chamB < PB) {
      int f0 = fpairs[2*idx], f1 = fpairs[2*idx+1];
      val = 1.0f - (fn_unit[3*f0]*fn_unit[3*f1] + fn_unit[3*f0+1]*fn_unit[3*f1+1]
                  + fn_unit[3*f0+2]*fn_unit[3*f1+2]);
    } else if (bid - chamB < PB + FB) {
      int f = idx - P;
      val = fabsf(e012[f]-avg) + fabsf(e012[F+f]-avg) + fabsf(e012[2*F+f]-avg);
    } else {
      float d = elen[idx - P - F] - avg;
      val = d * d;
    }
    blockRed1(red, val, &pf0[bid - chamB]);
  } else {
    int vb = bid - chamB - finB;
    vfinBody(psum, nv, vnorm, red, vb*256 + tid, V, &pl0[vb], &pl1[vb]);
  }
}

// ---- K5: final combine (1 block)
__global__ void k_combine(const float* __restrict__ pf0, const float* __restrict__ pl0,
                          const float* __restrict__ pl1, const float* __restrict__ pc,
                          const float* __restrict__ acc, float* __restrict__ out,
                          int V, int F, int E, int P, int Ns, int Nt) {
  __shared__ float red[8][4];
  int tid = threadIdx.x, wave = tid >> 6, lane = tid & 63;
  const int PB = P >> 8, FB = F >> 8, EB = E >> 8, VB = V >> 8, NsB = Ns >> 8, NtB = Nt >> 8;
  float s0=0,s1=0,s2=0,s3=0,s4=0,s5=0,s6=0,s7=0;
  for (int i = tid; i < PB; i += 256) s0 += pf0[i];
  for (int i = tid; i < FB; i += 256) s1 += pf0[PB + i];
  for (int i = tid; i < EB; i += 256) s2 += pf0[PB + FB + i];
  for (int i = tid; i < VB; i += 256) { s3 += pl0[i]; s4 += pl1[i]; }
  for (int i = tid; i < NsB; i += 256) s5 += pc[i];
  for (int i = tid; i < NtB; i += 256) s6 += pc[NsB + i];
  for (int i = tid; i < VB; i += 256) s7 += pc[NsB + NtB + i];
  s0=waveReduceAdd(s0); s1=waveReduceAdd(s1); s2=waveReduceAdd(s2); s3=waveReduceAdd(s3);
  s4=waveReduceAdd(s4); s5=waveReduceAdd(s5); s6=waveReduceAdd(s6); s7=waveReduceAdd(s7);
  if (lane == 0) { red[0][wave]=s0; red[1][wave]=s1; red[2][wave]=s2; red[3][wave]=s3;
                   red[4][wave]=s4; red[5][wave]=s5; red[6][wave]=s6; red[7][wave]=s7; }
  __syncthreads();
  if (tid == 0) {
    float t[8];
#pragma unroll
    for (int c = 0; c < 8; ++c) t[c] = red[c][0]+red[c][1]+red[c][2]+red[c][3];
    float loss = t[5]/(float)Ns + t[6]/(float)Nt;         // chamfer
    loss += 0.1f * ((acc[1] + t[1]) / (float)F);          // face
    loss += 0.1f * (t[2] / (float)E);                     // edge
    loss += 0.1f * (t[0] / (float)P);                     // normal
    loss += 0.1f * (acc[5] / (float)F);                   // smooth
    loss += 0.1f * (t[3] / (float)V);                     // laplacian
    loss += 0.5f * (t[4] / (3.0f * (float)V));            // consistency
    loss += 0.1f * (2.0f * t[7] / (float)V);              // symmetry (flip isometry)
    loss += 5.0f * (acc[11] / (float)V);                  // penetration
    out[0] = loss;
  }
}

extern "C" void kernel_launch(void* const* d_in, const int* in_sizes, int n_in,
                              void* d_out, int out_size, void* d_ws, size_t ws_size,
                              hipStream_t stream) {
  const float* verts   = (const float*)d_in[0];
  const float* deform  = (const float*)d_in[1];
  const float* bary    = (const float*)d_in[2];
  const float* s_trg   = (const float*)d_in[3];
  const float* vnorm   = (const float*)d_in[4];
  const int*   faces   = (const int*)d_in[5];
  const int*   edges   = (const int*)d_in[6];
  const int*   fpairs  = (const int*)d_in[7];
  const int*   sfi     = (const int*)d_in[8];
  float* out = (float*)d_out;

  const int V  = in_sizes[0] / 3;
  const int Ns = in_sizes[2] / 3;
  const int Nt = in_sizes[3] / 3;
  const int F  = in_sizes[5] / 3;
  const int E  = in_sizes[6] / 2;
  const int P  = in_sizes[7] / 2;

  float* ws   = (float*)d_ws;
  float* acc  = ws;                                   // 16
  float* pg0  = ws + 16;                              // 256
  float* pg1  = pg0 + 256;                            // 256
  float* pg2  = pg1 + 256;                            // 256
  float* pf0  = pg2 + 256;                            // 512
  float* pl0  = pf0 + 512;                            // 64
  float* pl1  = pl0 + 64;                             // 64
  float* pc   = pl1 + 64;                             // 256
  float* nv    = pc + 256;                            // 3V
  float* s_src = nv + 3*V;                            // 3Ns
  float* fn_u  = s_src + 3*Ns;                        // 3F
  float* fn_r  = fn_u + 3*F;                          // 3F
  float* e012  = fn_r + 3*F;                          // 3F
  float* elen  = e012 + 3*F;                          // E
  float* psum  = elen + E;                            // 28V
  float* recF  = psum + 28*V;                         // 8*(Ns+Nt+V)
  uint4* rrS  = (uint4*)recF;
  uint4* rrT  = (uint4*)(recF + 8*Ns);
  uint4* rrNf = (uint4*)(recF + 8*Ns + 8*Nt);

  size_t fixedEnd = (size_t)(recF - ws) + 8*(size_t)(Ns + Nt + V);
  size_t wsFloats = ws_size / sizeof(float);
  auto pchF = [&](int shC) {
    return (size_t)(Nt >> shC)*Ns + (size_t)(Ns >> shC)*Nt + (size_t)(V >> shC)*V;
  };
  int shC = 0; bool disjoint = true;
  for (int c = 10; c <= 12; ++c)
    if (fixedEnd + pchF(c) <= wsFloats) { shC = c; break; }
  if (!shC) { shC = 12; disjoint = false; }
  const int nb1 = Nt >> shC, nb2 = Ns >> shC, nb3 = V >> shC;
  float* pchBase = disjoint ? (recF + 8*(Ns + Nt + V)) : psum;
  float* pch1 = pchBase;
  float* pch2 = pch1 + (size_t)nb1 * Ns;
  float* pch3 = pch2 + (size_t)nb2 * Nt;

  int nGeom = (V + F + E + Ns + Nt) / 256;
  k_geom<<<nGeom, 256, 0, stream>>>(verts, deform, vnorm, bary, faces, edges, sfi,
                                    s_trg, nv, s_src, e012, fn_u, fn_r, elen,
                                    rrS, rrT, rrNf, pg0, pg1, pg2, V, F, E, Ns);

  int nCham = (Ns >> 9) * nb1 + (Nt >> 9) * nb2 + (V >> 9) * nb3;
  if (disjoint) {
    int grid = nCham + 513;   // chamfer + 512 scatter + 1 reduceG
    switch (shC) {
      case 10: k_mega<2><<<grid, 256, 0, stream>>>(rrS, rrT, rrNf, pch1, pch2, pch3,
                 faces, edges, fn_r, nv, psum, pg0, pg1, pg2, acc, Ns, Nt, V, F, E, nCham); break;
      case 11: k_mega<4><<<grid, 256, 0, stream>>>(rrS, rrT, rrNf, pch1, pch2, pch3,
                 faces, edges, fn_r, nv, psum, pg0, pg1, pg2, acc, Ns, Nt, V, F, E, nCham); break;
      default: k_mega<8><<<grid, 256, 0, stream>>>(rrS, rrT, rrNf, pch1, pch2, pch3,
                 faces, edges, fn_r, nv, psum, pg0, pg1, pg2, acc, Ns, Nt, V, F, E, nCham); break;
    }
  } else {
    k_scatterR<<<513, 256, 0, stream>>>(faces, edges, fn_r, nv, psum,
                                        pg0, pg1, pg2, acc, V, F, E);
    k_vfinSolo<<<V/256, 256, 0, stream>>>(psum, nv, vnorm, pl0, pl1, V);
    k_mega<8><<<nCham, 256, 0, stream>>>(rrS, rrT, rrNf, pch1, pch2, pch3,
                 faces, edges, fn_r, nv, psum, pg0, pg1, pg2, acc, Ns, Nt, V, F, E, nCham);
  }

  int chamB = (Ns + Nt + V) >> 8, finB = (P + F + E) >> 8;
  int vfinB = disjoint ? (V >> 8) : 0;
  k_fin<<<chamB + finB + vfinB, 256, 0, stream>>>(pch1, pch2, pch3, s_src, s_trg, nv, pc,
                                                  fpairs, fn_u, e012, elen, acc, pf0,
                                                  psum, vnorm, pl0, pl1,
                                                  Ns, Nt, V, nb1, nb2, nb3, P, F, E);
  k_combine<<<1, 256, 0, stream>>>(pf0, pl0, pl1, pc, acc, out, V, F, E, P, Ns, Nt);
}

// Round 14
// 63.074 us; speedup vs baseline: 1.5032x; 1.3004x over previous
//
#include <hip/hip_runtime.h>

#define MEPS 1e-6f
#define FINF 3.402823466e38f

typedef short bf16x8 __attribute__((ext_vector_type(8)));   // 8 bf16 (4 VGPRs)
typedef float f32x16 __attribute__((ext_vector_type(16)));  // MFMA 32x32 C/D

// async 16B global->LDS DMA (no VGPR round-trip)
__device__ __forceinline__ void load_lds16(const uint4* g, uint4* l) {
  __builtin_amdgcn_global_load_lds(
      (const __attribute__((address_space(1))) unsigned int*)g,
      (__attribute__((address_space(3))) unsigned int*)l, 16, 0, 0);
}

// bf16 round-to-nearest-even
__device__ __forceinline__ unsigned short bfr(float f) {
  unsigned u = __float_as_uint(f);
  return (unsigned short)((u + 0x7FFFu + ((u >> 16) & 1u)) >> 16);
}
__device__ __forceinline__ float bff(unsigned short h) {
  return __uint_as_float(((unsigned)h) << 16);
}
// Row-record (MFMA A-operand, b-points), 16 bf16 = 32B
__device__ __forceinline__ void writeRow(uint4* __restrict__ dst, int i,
                                         float x, float y, float z) {
  unsigned short hx = bfr(x); float fhx = bff(hx); unsigned short lx = bfr(x - fhx);
  unsigned short hy = bfr(y); float fhy = bff(hy); unsigned short ly = bfr(y - fhy);
  unsigned short hz = bfr(z); float fhz = bff(hz); unsigned short lz = bfr(z - fhz);
  float s = fmaf(x, x, fmaf(y, y, z * z));
  unsigned short hs = bfr(s); unsigned short ls = bfr(s - bff(hs));
  uint4 r0, r1;
  r0.x = (unsigned)hx | ((unsigned)hx << 16);
  r0.y = (unsigned)lx | ((unsigned)hy << 16);
  r0.z = (unsigned)hy | ((unsigned)ly << 16);
  r0.w = (unsigned)hz | ((unsigned)hz << 16);
  r1.x = (unsigned)lz | ((unsigned)hs << 16);
  r1.y = (unsigned)ls;
  r1.z = 0u; r1.w = 0u;
  dst[2*i] = r0; dst[2*i+1] = r1;
}

__device__ __forceinline__ float waveReduceAdd(float v) {
#pragma unroll
  for (int off = 32; off > 0; off >>= 1) v += __shfl_down(v, off, 64);
  return v;
}
__device__ __forceinline__ void blockRed1(float* red, float v, float* out) {
  int wave = threadIdx.x >> 6, lane = threadIdx.x & 63;
  v = waveReduceAdd(v);
  if (lane == 0) red[wave] = v;
  __syncthreads();
  if (threadIdx.x == 0) out[0] = red[0] + red[1] + red[2] + red[3];
}
__device__ __forceinline__ void blockRed2(float* red, float v0, float v1,
                                          float* o0, float* o1) {
  int wave = threadIdx.x >> 6, lane = threadIdx.x & 63;
  v0 = waveReduceAdd(v0); v1 = waveReduceAdd(v1);
  if (lane == 0) { red[wave] = v0; red[4 + wave] = v1; }
  __syncthreads();
  if (threadIdx.x == 0) {
    o0[0] = red[0] + red[1] + red[2] + red[3];
    o1[0] = red[4] + red[5] + red[6] + red[7];
  }
}
__device__ __forceinline__ void blockRed3(float* red, float v0, float v1, float v2,
                                          float* o0, float* o1, float* o2) {
  int wave = threadIdx.x >> 6, lane = threadIdx.x & 63;
  v0 = waveReduceAdd(v0); v1 = waveReduceAdd(v1); v2 = waveReduceAdd(v2);
  if (lane == 0) { red[wave] = v0; red[4 + wave] = v1; red[8 + wave] = v2; }
  __syncthreads();
  if (threadIdx.x == 0) {
    o0[0] = red[0] + red[1] + red[2] + red[3];
    o1[0] = red[4] + red[5] + red[6] + red[7];
    o2[0] = red[8] + red[9] + red[10] + red[11];
  }
}

// ---- K1: fused streaming pass + bf16 record emission. Branch uniform per block.
__global__ __launch_bounds__(256)
void k_geom(const float* __restrict__ verts, const float* __restrict__ deform,
            const float* __restrict__ vnorm, const float* __restrict__ bary,
            const int* __restrict__ faces, const int* __restrict__ edges,
            const int* __restrict__ sfi, const float* __restrict__ strg,
            float* __restrict__ nv, float* __restrict__ s_src,
            float* __restrict__ e012, float* __restrict__ fn_unit,
            float* __restrict__ fn_raw, float* __restrict__ elen,
            uint4* __restrict__ rrS, uint4* __restrict__ rrT, uint4* __restrict__ rrNf,
            float* __restrict__ pg0, float* __restrict__ pg1, float* __restrict__ pg2,
            int V, int F, int E, int Ns) {
  __shared__ float red[12];
  const int bid = blockIdx.x;
  const int idx = bid * 256 + threadIdx.x;
  const int VB = V >> 8, FB = F >> 8, EB = E >> 8, SB = Ns >> 8;
  if (bid < VB) {
    int i = idx;
    float dx = deform[3*i], dy = deform[3*i+1], dz = deform[3*i+2];
    float nx = verts[3*i] + dx, ny = verts[3*i+1] + dy, nz = verts[3*i+2] + dz;
    nv[3*i] = nx; nv[3*i+1] = ny; nv[3*i+2] = nz;
    writeRow(rrNf, i, -nx, ny, nz);   // flipped cloud (B-side of sym pass)
    float dot = dx*vnorm[3*i] + dy*vnorm[3*i+1] + dz*vnorm[3*i+2];
    blockRed1(red, fabsf(fminf(dot, -0.1f)), &pg0[bid]);
  } else if (bid < VB + FB) {
    int f = idx - V;
    int i0 = faces[3*f], i1 = faces[3*f+1], i2 = faces[3*f+2];
    float d0x = deform[3*i0], d0y = deform[3*i0+1], d0z = deform[3*i0+2];
    float d1x = deform[3*i1], d1y = deform[3*i1+1], d1z = deform[3*i1+2];
    float d2x = deform[3*i2], d2y = deform[3*i2+1], d2z = deform[3*i2+2];
    float v0x = verts[3*i0]+d0x, v0y = verts[3*i0+1]+d0y, v0z = verts[3*i0+2]+d0z;
    float v1x = verts[3*i1]+d1x, v1y = verts[3*i1+1]+d1y, v1z = verts[3*i1+2]+d1z;
    float v2x = verts[3*i2]+d2x, v2y = verts[3*i2+1]+d2y, v2z = verts[3*i2+2]+d2z;
    float e0 = sqrtf((v0x-v1x)*(v0x-v1x)+(v0y-v1y)*(v0y-v1y)+(v0z-v1z)*(v0z-v1z));
    float e1 = sqrtf((v1x-v2x)*(v1x-v2x)+(v1y-v2y)*(v1y-v2y)+(v1z-v2z)*(v1z-v2z));
    float e2 = sqrtf((v2x-v0x)*(v2x-v0x)+(v2y-v0y)*(v2y-v0y)+(v2z-v0z)*(v2z-v0z));
    e012[f] = e0; e012[F+f] = e1; e012[2*F+f] = e2;
    float ax = v1x-v0x, ay = v1y-v0y, az = v1z-v0z;
    float bx = v2x-v0x, by = v2y-v0y, bz = v2z-v0z;
    float fnx = ay*bz - az*by, fny = az*bx - ax*bz, fnz = ax*by - ay*bx;
    fn_raw[3*f] = fnx; fn_raw[3*f+1] = fny; fn_raw[3*f+2] = fnz;
    float inv = 1.0f / (sqrtf(fnx*fnx+fny*fny+fnz*fnz) + MEPS);
    fn_unit[3*f] = fnx*inv; fn_unit[3*f+1] = fny*inv; fn_unit[3*f+2] = fnz*inv;
    float s0 = sqrtf(d0x*d0x + d0y*d0y + d0z*d0z);
    float s1 = sqrtf(d1x*d1x + d1y*d1y + d1z*d1z);
    float s2 = sqrtf(d2x*d2x + d2y*d2y + d2z*d2z);
    blockRed3(red, e0 + e1 + e2,
              fabsf(e0-e1) + fabsf(e1-e2) + fabsf(e2-e0),
              fabsf(s0-s1) + fabsf(s1-s2) + fabsf(s2-s0),
              &pg0[bid], &pg1[bid], &pg2[bid]);
  } else if (bid < VB + FB + EB) {
    int e = idx - V - F;
    int a = edges[2*e], b = edges[2*e+1];
    float pax = verts[3*a]+deform[3*a], pay = verts[3*a+1]+deform[3*a+1], paz = verts[3*a+2]+deform[3*a+2];
    float pbx = verts[3*b]+deform[3*b], pby = verts[3*b+1]+deform[3*b+1], pbz = verts[3*b+2]+deform[3*b+2];
    elen[e] = sqrtf((pax-pbx)*(pax-pbx)+(pay-pby)*(pay-pby)+(paz-pbz)*(paz-pbz));
  } else if (bid < VB + FB + EB + SB) {
    int s = idx - V - F - E;
    int f = sfi[s];
    int i0 = faces[3*f], i1 = faces[3*f+1], i2 = faces[3*f+2];
    float w0 = bary[3*s], w1 = bary[3*s+1], w2 = bary[3*s+2];
    float sx = w0*(verts[3*i0]  +deform[3*i0])   + w1*(verts[3*i1]  +deform[3*i1])   + w2*(verts[3*i2]  +deform[3*i2]);
    float sy = w0*(verts[3*i0+1]+deform[3*i0+1]) + w1*(verts[3*i1+1]+deform[3*i1+1]) + w2*(verts[3*i2+1]+deform[3*i2+1]);
    float sz = w0*(verts[3*i0+2]+deform[3*i0+2]) + w1*(verts[3*i1+2]+deform[3*i1+2]) + w2*(verts[3*i2+2]+deform[3*i2+2]);
    s_src[3*s] = sx; s_src[3*s+1] = sy; s_src[3*s+2] = sz;
    writeRow(rrS, s, sx, sy, sz);
  } else {
    int t = idx - V - F - E - Ns;
    writeRow(rrT, t, strg[3*t], strg[3*t+1], strg[3*t+2]);
  }
}

// scatter body (aliased LDS >= 4KB) — 512 scatter blocks + 1 reduceG block.
__device__ __forceinline__ void scatterBody(
    int sb, int tid, float* ldsF,
    const int* __restrict__ faces, const int* __restrict__ edges,
    const float* __restrict__ fn_raw, const float* __restrict__ nv,
    float* __restrict__ psum,
    const float* __restrict__ pg0, const float* __restrict__ pg1,
    const float* __restrict__ pg2, float* __restrict__ acc,
    int V, int F, int E) {
  if (sb == 512) {  // reduceG
    float* red = ldsF;
    int wave = tid >> 6, lane = tid & 63;
    const int VB = V >> 8, FB = F >> 8;
    float pen = 0, es = 0, l1 = 0, sm = 0;
    for (int i = tid; i < VB; i += 256) pen += pg0[i];
    for (int i = VB + tid; i < VB + FB; i += 256) { es += pg0[i]; l1 += pg1[i]; sm += pg2[i]; }
    pen = waveReduceAdd(pen); es = waveReduceAdd(es);
    l1 = waveReduceAdd(l1);   sm = waveReduceAdd(sm);
    if (lane == 0) { red[wave] = pen; red[4+wave] = es; red[8+wave] = l1; red[12+wave] = sm; }
    __syncthreads();
    if (tid == 0) {
      acc[11] = red[0]+red[1]+red[2]+red[3];
      acc[0]  = red[4]+red[5]+red[6]+red[7];
      acc[1]  = red[8]+red[9]+red[10]+red[11];
      acc[5]  = red[12]+red[13]+red[14]+red[15];
    }
    return;
  }
  float* lds = ldsF;   // [4][256]
#pragma unroll
  for (int c = 0; c < 4; ++c) lds[c*256 + tid] = 0.f;
  __syncthreads();
  if (sb < 256) {
    int r = sb & 63, s = sb >> 6;
    int base = r << 8;
    int fs = F >> 2;
    for (int f = s*fs + tid; f < s*fs + fs; f += 256) {
      int i0 = faces[3*f], i1 = faces[3*f+1], i2 = faces[3*f+2];
      unsigned r0 = (unsigned)(i0-base), r1 = (unsigned)(i1-base), r2 = (unsigned)(i2-base);
      if ((r0 < 256u) | (r1 < 256u) | (r2 < 256u)) {
        float fx = fn_raw[3*f], fy = fn_raw[3*f+1], fz = fn_raw[3*f+2];
        if (r0 < 256u) { atomicAdd(&lds[r0],fx); atomicAdd(&lds[256+r0],fy); atomicAdd(&lds[512+r0],fz); }
        if (r1 < 256u) { atomicAdd(&lds[r1],fx); atomicAdd(&lds[256+r1],fy); atomicAdd(&lds[512+r1],fz); }
        if (r2 < 256u) { atomicAdd(&lds[r2],fx); atomicAdd(&lds[256+r2],fy); atomicAdd(&lds[512+r2],fz); }
      }
    }
    __syncthreads();
#pragma unroll
    for (int c = 0; c < 3; ++c) psum[(size_t)(s*7 + 4 + c)*V + base + tid] = lds[c*256 + tid];
  } else {
    int b2 = sb - 256;
    int r = b2 & 63, s = b2 >> 6;
    int base = r << 8;
    int es = E >> 2;
    for (int e = s*es + tid; e < s*es + es; e += 256) {
      int a = edges[2*e], b = edges[2*e+1];
      unsigned ra = (unsigned)(a-base), rb = (unsigned)(b-base);
      if (ra < 256u) {
        atomicAdd(&lds[ra], nv[3*b]); atomicAdd(&lds[256+ra], nv[3*b+1]);
        atomicAdd(&lds[512+ra], nv[3*b+2]); atomicAdd(&lds[768+ra], 1.0f);
      }
      if (rb < 256u) {
        atomicAdd(&lds[rb], nv[3*a]); atomicAdd(&lds[256+rb], nv[3*a+1]);
        atomicAdd(&lds[512+rb], nv[3*a+2]); atomicAdd(&lds[768+rb], 1.0f);
      }
    }
    __syncthreads();
#pragma unroll
    for (int c = 0; c < 4; ++c) psum[(size_t)(s*7 + c)*V + base + tid] = lds[c*256 + tid];
  }
}

// standalone scatter (aliased-ws fallback only)
__global__ __launch_bounds__(256)
void k_scatterR(const int* __restrict__ faces, const int* __restrict__ edges,
                const float* __restrict__ fn_raw, const float* __restrict__ nv,
                float* __restrict__ psum,
                const float* __restrict__ pg0, const float* __restrict__ pg1,
                const float* __restrict__ pg2, float* __restrict__ acc,
                int V, int F, int E) {
  __shared__ float lds[1024];
  scatterBody(blockIdx.x, threadIdx.x, lds, faces, edges, fn_raw, nv, psum,
              pg0, pg1, pg2, acc, V, F, E);
}

__device__ __forceinline__ void vfinBody(const float* __restrict__ psum,
                                         const float* __restrict__ nv,
                                         const float* __restrict__ vnorm,
                                         float* red, int v, int V,
                                         float* o0, float* o1) {
  float nbx=0, nby=0, nbz=0, dg=0, vx=0, vy=0, vz=0;
#pragma unroll
  for (int s = 0; s < 4; ++s) {
    nbx += psum[(size_t)(s*7+0)*V + v];
    nby += psum[(size_t)(s*7+1)*V + v];
    nbz += psum[(size_t)(s*7+2)*V + v];
    dg  += psum[(size_t)(s*7+3)*V + v];
    vx  += psum[(size_t)(s*7+4)*V + v];
    vy  += psum[(size_t)(s*7+5)*V + v];
    vz  += psum[(size_t)(s*7+6)*V + v];
  }
  float inv = 1.0f / fmaxf(dg, 1.0f);
  float lx = nbx*inv - nv[3*v];
  float ly = nby*inv - nv[3*v+1];
  float lz = nbz*inv - nv[3*v+2];
  float lap = sqrtf(lx*lx + ly*ly + lz*lz);
  float vinv = 1.0f / (sqrtf(vx*vx + vy*vy + vz*vz) + MEPS);
  float dx = vx*vinv - vnorm[3*v];
  float dy = vy*vinv - vnorm[3*v+1];
  float dz = vz*vinv - vnorm[3*v+2];
  blockRed2(red, lap, dx*dx + dy*dy + dz*dz, o0, o1);
}

__global__ __launch_bounds__(256)
void k_vfinSolo(const float* __restrict__ psum, const float* __restrict__ nv,
                const float* __restrict__ vnorm,
                float* __restrict__ pl0, float* __restrict__ pl1, int V) {
  __shared__ float red[8];
  vfinBody(psum, nv, vnorm, red, blockIdx.x*256 + threadIdx.x, V,
           &pl0[blockIdx.x], &pl1[blockIdx.x]);
}

// left-chained so clang fuses to v_min3_f32
__device__ __forceinline__ float m3(float a, float b, float c) {
  return fminf(fminf(a, b), c);
}
__device__ __forceinline__ float rmin16(float m, f32x16 d) {
  float u0 = m3(d[0],  d[1],  d[2]);
  float u1 = m3(d[3],  d[4],  d[5]);
  float u2 = m3(d[6],  d[7],  d[8]);
  float u3 = m3(d[9],  d[10], d[11]);
  float u4 = m3(d[12], d[13], d[14]);
  float v0 = m3(u0, u1, u2);
  float v1 = m3(u3, u4, d[15]);
  return m3(m, v0, v1);
}

// ---- K3: MEGA kernel. Blocks [0, nScat): scatter + reduceG (short, memory-
// bound, co-scheduled with chamfer from t=0). Blocks [nScat, nScat+nCham):
// MFMA chamfer: 4 waves x 128 a-cols; chunk = STAGES x 512 b-records; DMA
// double-buffered staging overlapped with compute.
template<int STAGES>
__global__ __launch_bounds__(256, 4)
void k_mega(const uint4* __restrict__ rrS, const uint4* __restrict__ rrT,
            const uint4* __restrict__ rrNf,
            float* __restrict__ pch1, float* __restrict__ pch2, float* __restrict__ pch3,
            const int* __restrict__ faces, const int* __restrict__ edges,
            const float* __restrict__ fn_raw, const float* __restrict__ nv,
            float* __restrict__ psum,
            const float* __restrict__ pg0, const float* __restrict__ pg1,
            const float* __restrict__ pg2, float* __restrict__ acc,
            int Ns, int Nt, int V, int F, int E, int nScat) {
  __shared__ uint4 sB[2][1024];          // 32 KB; scatter/reduceG alias onto it
  const int tid = threadIdx.x;
  if (blockIdx.x < nScat) {
    scatterBody(blockIdx.x, tid, (float*)sB, faces, edges, fn_raw, nv, psum,
                pg0, pg1, pg2, acc, V, F, E);
    return;
  }
  const int bid = blockIdx.x - nScat;
  const int ln = tid & 63, wv = tid >> 6;
  const int col = ln & 31, half = ln >> 5;
  const int shC = (STAGES == 4) ? 11 : 12;
  const int aT1 = Ns >> 9, aT2 = Nt >> 9, aT3 = V >> 9;
  const int nb1 = Nt >> shC, nb2 = Ns >> shC;
  const int B1 = aT1 * nb1, B2 = B1 + aT2 * nb2;
  const uint4 *cr, *rr; float* pch; int at, bc, Na; float sx;
  if (bid < B1)      { cr = rrS;  rr = rrT;  pch = pch1; Na = Ns; at = bid % aT1; bc = bid / aT1; sx = -2.f; }
  else if (bid < B2) { int l = bid - B1; cr = rrT;  rr = rrS;  pch = pch2; Na = Nt; at = l % aT2; bc = l / aT2; sx = -2.f; }
  else               { int l = bid - B2; cr = rrNf; rr = rrNf; pch = pch3; Na = V;  at = l % aT3; bc = l / aT3; sx = 2.f; }
  // sx=+2 for sym pass: rrNf stores -x; col side needs -2*(+x) = +2*(-x).
  const int aBase = (at << 9) + (wv << 7);

  // Build 4 col-frag (B-operand) sets from the col cloud's records.
  bf16x8 bfrag[4];
#pragma unroll
  for (int s = 0; s < 4; ++s) {
    const uint4* crp = cr + ((size_t)(aBase + (s << 5) + col) << 1);
    uint4 q0 = crp[0], q1 = crp[1];
    unsigned short e0 = (unsigned short)(q0.x & 0xFFFFu);
    unsigned short e2 = (unsigned short)(q0.y & 0xFFFFu);
    unsigned short e3 = (unsigned short)(q0.y >> 16);
    unsigned short e5 = (unsigned short)(q0.z >> 16);
    unsigned short e6 = (unsigned short)(q0.w & 0xFFFFu);
    unsigned short e8 = (unsigned short)(q1.x & 0xFFFFu);
    unsigned short a0 = bfr(sx   * bff(e0));   // +-2*hx
    unsigned short a1 = bfr(sx   * bff(e2));   // +-2*lx
    unsigned short a3 = bfr(-2.f * bff(e3));   // -2*hy
    unsigned short a4 = bfr(-2.f * bff(e5));   // -2*ly
    unsigned short a6 = bfr(-2.f * bff(e6));   // -2*hz
    unsigned short a7 = bfr(-2.f * bff(e8));   // -2*lz
    uint4 bb;
    if (half == 0) {           // k0..7
      bb.x = (unsigned)a0 | ((unsigned)a1 << 16);
      bb.y = (unsigned)a0 | ((unsigned)a3 << 16);
      bb.z = (unsigned)a4 | ((unsigned)a3 << 16);
      bb.w = (unsigned)a6 | ((unsigned)a7 << 16);
    } else {                   // k8..15: [-2hz, 1, 1, 0...]
      bb.x = (unsigned)a6 | (0x3F80u << 16);
      bb.y = 0x3F80u;
      bb.z = 0u; bb.w = 0u;
    }
    bfrag[s] = __builtin_bit_cast(bf16x8, bb);
  }

  float m0 = FINF, m1 = FINF, m2 = FINF, m3v = FINF;
  f32x16 zz = {0.f,0.f,0.f,0.f,0.f,0.f,0.f,0.f,0.f,0.f,0.f,0.f,0.f,0.f,0.f,0.f};
  const int bBase = bc << shC;

  auto stage_dma = [&](int stIdx, int buf) {
    const uint4* src = rr + ((size_t)(bBase + (stIdx << 9)) << 1);
#pragma unroll
    for (int i = 0; i < 4; ++i) {
      int lc = tid + (i << 8);               // lds chunk 0..1023
      int h = lc >> 9, rec = lc & 511;
      load_lds16(src + ((rec << 1) + h), &sB[buf][lc]);
    }
  };

  stage_dma(0, 0);
  __syncthreads();                            // vmcnt(0) drain: buf0 ready
  int cur = 0;
#pragma unroll 1
  for (int st = 0; st < STAGES; ++st) {
    if (st + 1 < STAGES) stage_dma(st + 1, cur ^ 1);   // overlaps with compute
    const bf16x8* lp = (const bf16x8*)&sB[cur][half << 9];
    bf16x8 af = lp[col];
#pragma unroll
    for (int bt = 0; bt < 16; ++bt) {
      bf16x8 curf = af;
      if (bt < 15) af = lp[((bt + 1) << 5) + col];   // prefetch next record-frag
      {
        f32x16 d = __builtin_amdgcn_mfma_f32_32x32x16_bf16(curf, bfrag[0], zz, 0, 0, 0);
        m0 = rmin16(m0, d);
      }
      {
        f32x16 d = __builtin_amdgcn_mfma_f32_32x32x16_bf16(curf, bfrag[1], zz, 0, 0, 0);
        m1 = rmin16(m1, d);
      }
      {
        f32x16 d = __builtin_amdgcn_mfma_f32_32x32x16_bf16(curf, bfrag[2], zz, 0, 0, 0);
        m2 = rmin16(m2, d);
      }
      {
        f32x16 d = __builtin_amdgcn_mfma_f32_32x32x16_bf16(curf, bfrag[3], zz, 0, 0, 0);
        m3v = rmin16(m3v, d);
      }
    }
    __syncthreads();   // drains next-stage DMA (already landed) + reader sync
    cur ^= 1;
  }
  float mm0 = fminf(m0,  __shfl_xor(m0, 32));
  float mm1 = fminf(m1,  __shfl_xor(m1, 32));
  float mm2 = fminf(m2,  __shfl_xor(m2, 32));
  float mm3 = fminf(m3v, __shfl_xor(m3v, 32));
  if (ln < 32) {
    size_t base = (size_t)bc * Na + aBase + col;
    pch[base]      = mm0;
    pch[base + 32] = mm1;
    pch[base + 64] = mm2;
    pch[base + 96] = mm3;
  }
}

// ---- K4: fused finalize: chamfer per-point partials, avg terms, (opt) vfin.
__global__ __launch_bounds__(256)
void k_fin(const float* __restrict__ pch1, const float* __restrict__ pch2,
           const float* __restrict__ pch3,
           const float* __restrict__ s_src, const float* __restrict__ s_trg,
           const float* __restrict__ nv, float* __restrict__ pc,
           const int* __restrict__ fpairs, const float* __restrict__ fn_unit,
           const float* __restrict__ e012, const float* __restrict__ elen,
           const float* __restrict__ acc, float* __restrict__ pf0,
           const float* __restrict__ psum, const float* __restrict__ vnorm,
           float* __restrict__ pl0, float* __restrict__ pl1,
           int Ns, int Nt, int V, int c1, int c2, int c3,
           int P, int F, int E) {
  __shared__ float red[8];
  const int bid = blockIdx.x;
  const int tid = threadIdx.x;
  const int chamB = (Ns + Nt + V) >> 8;
  const int finB = (P + F + E) >> 8;
  if (bid < chamB) {
    int idx = bid * 256 + tid;
    const float* A; const float* pch; int li, nc, Na;
    if (idx < Ns)           { A = s_src; pch = pch1; li = idx;           nc = c1; Na = Ns; }
    else if (idx < Ns + Nt) { A = s_trg; pch = pch2; li = idx - Ns;      nc = c2; Na = Nt; }
    else                    { A = nv;    pch = pch3; li = idx - Ns - Nt; nc = c3; Na = V; }
    float mn = FINF;
#pragma unroll 4
    for (int c = 0; c < nc; ++c) mn = fminf(mn, pch[(size_t)c * Na + li]);
    float x = A[3*li], y = A[3*li+1], z = A[3*li+2];
    blockRed1(red, x*x + y*y + z*z + mn, &pc[bid]);
  } else if (bid < chamB + finB) {
    int idx = (bid - chamB) * 256 + tid;
    const int PB = P >> 8, FB = F >> 8;
    float avg = acc[0] / (3.0f * (float)F);
    float val;
    if (bid - chamB < PB) {
      int f0 = fpairs[2*idx], f1 = fpairs[2*idx+1];
      val = 1.0f - (fn_unit[3*f0]*fn_unit[3*f1] + fn_unit[3*f0+1]*fn_unit[3*f1+1]
                  + fn_unit[3*f0+2]*fn_unit[3*f1+2]);
    } else if (bid - chamB < PB + FB) {
      int f = idx - P;
      val = fabsf(e012[f]-avg) + fabsf(e012[F+f]-avg) + fabsf(e012[2*F+f]-avg);
    } else {
      float d = elen[idx - P - F] - avg;
      val = d * d;
    }
    blockRed1(red, val, &pf0[bid - chamB]);
  } else {
    int vb = bid - chamB - finB;
    vfinBody(psum, nv, vnorm, red, vb*256 + tid, V, &pl0[vb], &pl1[vb]);
  }
}

// ---- K5: final combine (1 block)
__global__ void k_combine(const float* __restrict__ pf0, const float* __restrict__ pl0,
                          const float* __restrict__ pl1, const float* __restrict__ pc,
                          const float* __restrict__ acc, float* __restrict__ out,
                          int V, int F, int E, int P, int Ns, int Nt) {
  __shared__ float red[8][4];
  int tid = threadIdx.x, wave = tid >> 6, lane = tid & 63;
  const int PB = P >> 8, FB = F >> 8, EB = E >> 8, VB = V >> 8, NsB = Ns >> 8, NtB = Nt >> 8;
  float s0=0,s1=0,s2=0,s3=0,s4=0,s5=0,s6=0,s7=0;
  for (int i = tid; i < PB; i += 256) s0 += pf0[i];
  for (int i = tid; i < FB; i += 256) s1 += pf0[PB + i];
  for (int i = tid; i < EB; i += 256) s2 += pf0[PB + FB + i];
  for (int i = tid; i < VB; i += 256) { s3 += pl0[i]; s4 += pl1[i]; }
  for (int i = tid; i < NsB; i += 256) s5 += pc[i];
  for (int i = tid; i < NtB; i += 256) s6 += pc[NsB + i];
  for (int i = tid; i < VB; i += 256) s7 += pc[NsB + NtB + i];
  s0=waveReduceAdd(s0); s1=waveReduceAdd(s1); s2=waveReduceAdd(s2); s3=waveReduceAdd(s3);
  s4=waveReduceAdd(s4); s5=waveReduceAdd(s5); s6=waveReduceAdd(s6); s7=waveReduceAdd(s7);
  if (lane == 0) { red[0][wave]=s0; red[1][wave]=s1; red[2][wave]=s2; red[3][wave]=s3;
                   red[4][wave]=s4; red[5][wave]=s5; red[6][wave]=s6; red[7][wave]=s7; }
  __syncthreads();
  if (tid == 0) {
    float t[8];
#pragma unroll
    for (int c = 0; c < 8; ++c) t[c] = red[c][0]+red[c][1]+red[c][2]+red[c][3];
    float loss = t[5]/(float)Ns + t[6]/(float)Nt;         // chamfer
    loss += 0.1f * ((acc[1] + t[1]) / (float)F);          // face
    loss += 0.1f * (t[2] / (float)E);                     // edge
    loss += 0.1f * (t[0] / (float)P);                     // normal
    loss += 0.1f * (acc[5] / (float)F);                   // smooth
    loss += 0.1f * (t[3] / (float)V);                     // laplacian
    loss += 0.5f * (t[4] / (3.0f * (float)V));            // consistency
    loss += 0.1f * (2.0f * t[7] / (float)V);              // symmetry (flip isometry)
    loss += 5.0f * (acc[11] / (float)V);                  // penetration
    out[0] = loss;
  }
}

extern "C" void kernel_launch(void* const* d_in, const int* in_sizes, int n_in,
                              void* d_out, int out_size, void* d_ws, size_t ws_size,
                              hipStream_t stream) {
  const float* verts   = (const float*)d_in[0];
  const float* deform  = (const float*)d_in[1];
  const float* bary    = (const float*)d_in[2];
  const float* s_trg   = (const float*)d_in[3];
  const float* vnorm   = (const float*)d_in[4];
  const int*   faces   = (const int*)d_in[5];
  const int*   edges   = (const int*)d_in[6];
  const int*   fpairs  = (const int*)d_in[7];
  const int*   sfi     = (const int*)d_in[8];
  float* out = (float*)d_out;

  const int V  = in_sizes[0] / 3;
  const int Ns = in_sizes[2] / 3;
  const int Nt = in_sizes[3] / 3;
  const int F  = in_sizes[5] / 3;
  const int E  = in_sizes[6] / 2;
  const int P  = in_sizes[7] / 2;

  float* ws   = (float*)d_ws;
  float* acc  = ws;                                   // 16
  float* pg0  = ws + 16;                              // 256
  float* pg1  = pg0 + 256;                            // 256
  float* pg2  = pg1 + 256;                            // 256
  float* pf0  = pg2 + 256;                            // 512
  float* pl0  = pf0 + 512;                            // 64
  float* pl1  = pl0 + 64;                             // 64
  float* pc   = pl1 + 64;                             // 256
  float* nv    = pc + 256;                            // 3V
  float* s_src = nv + 3*V;                            // 3Ns
  float* fn_u  = s_src + 3*Ns;                        // 3F
  float* fn_r  = fn_u + 3*F;                          // 3F
  float* e012  = fn_r + 3*F;                          // 3F
  float* elen  = e012 + 3*F;                          // E
  float* psum  = elen + E;                            // 28V
  float* recF  = psum + 28*V;                         // 8*(Ns+Nt+V)
  uint4* rrS  = (uint4*)recF;
  uint4* rrT  = (uint4*)(recF + 8*Ns);
  uint4* rrNf = (uint4*)(recF + 8*Ns + 8*Nt);

  size_t fixedEnd = (size_t)(recF - ws) + 8*(size_t)(Ns + Nt + V);
  size_t wsFloats = ws_size / sizeof(float);
  auto pchF = [&](int shC) {
    return (size_t)(Nt >> shC)*Ns + (size_t)(Ns >> shC)*Nt + (size_t)(V >> shC)*V;
  };
  int shC = 0; bool disjoint = true;
  for (int c = 11; c <= 12; ++c)
    if (fixedEnd + pchF(c) <= wsFloats) { shC = c; break; }
  if (!shC) { shC = 12; disjoint = false; }
  const int nb1 = Nt >> shC, nb2 = Ns >> shC, nb3 = V >> shC;
  float* pchBase = disjoint ? (recF + 8*(Ns + Nt + V)) : psum;
  float* pch1 = pchBase;
  float* pch2 = pch1 + (size_t)nb1 * Ns;
  float* pch3 = pch2 + (size_t)nb2 * Nt;

  int nGeom = (V + F + E + Ns + Nt) / 256;
  k_geom<<<nGeom, 256, 0, stream>>>(verts, deform, vnorm, bary, faces, edges, sfi,
                                    s_trg, nv, s_src, e012, fn_u, fn_r, elen,
                                    rrS, rrT, rrNf, pg0, pg1, pg2, V, F, E, Ns);

  int nCham = (Ns >> 9) * nb1 + (Nt >> 9) * nb2 + (V >> 9) * nb3;
  if (disjoint) {
    int grid = 513 + nCham;   // scatter first, then chamfer
    if (shC == 11)
      k_mega<4><<<grid, 256, 0, stream>>>(rrS, rrT, rrNf, pch1, pch2, pch3,
               faces, edges, fn_r, nv, psum, pg0, pg1, pg2, acc, Ns, Nt, V, F, E, 513);
    else
      k_mega<8><<<grid, 256, 0, stream>>>(rrS, rrT, rrNf, pch1, pch2, pch3,
               faces, edges, fn_r, nv, psum, pg0, pg1, pg2, acc, Ns, Nt, V, F, E, 513);
  } else {
    k_scatterR<<<513, 256, 0, stream>>>(faces, edges, fn_r, nv, psum,
                                        pg0, pg1, pg2, acc, V, F, E);
    k_vfinSolo<<<V/256, 256, 0, stream>>>(psum, nv, vnorm, pl0, pl1, V);
    k_mega<8><<<nCham, 256, 0, stream>>>(rrS, rrT, rrNf, pch1, pch2, pch3,
               faces, edges, fn_r, nv, psum, pg0, pg1, pg2, acc, Ns, Nt, V, F, E, 0);
  }

  int chamB = (Ns + Nt + V) >> 8, finB = (P + F + E) >> 8;
  int vfinB = disjoint ? (V >> 8) : 0;
  k_fin<<<chamB + finB + vfinB, 256, 0, stream>>>(pch1, pch2, pch3, s_src, s_trg, nv, pc,
                                                  fpairs, fn_u, e012, elen, acc, pf0,
                                                  psum, vnorm, pl0, pl1,
                                                  Ns, Nt, V, nb1, nb2, nb3, P, F, E);
  k_combine<<<1, 256, 0, stream>>>(pf0, pl0, pl1, pc, acc, out, V, F, E, P, Ns, Nt);
}